// Round 3
// baseline (1914.224 us; speedup 1.0000x reference)
//
#include <hip/hip_runtime.h>
#include <math.h>

// Problem constants (match reference)
namespace {
constexpr int Bn = 64;    // batch
constexpr int Dn = 256;   // feature dim
constexpr int Tn = 24;    // words
constexpr int Rn = 17;
constexpr int Sn = Rn * Rn;  // 289 spatial
constexpr float G1 = 4.0f, G2 = 5.0f, G3 = 10.0f;
constexpr float EPSF = 1e-8f;
constexpr float NEGF = -1e30f;
constexpr int WSTR = 24;   // W_lds row stride (floats); 96B rows, 16B-aligned
constexpr int ASTR = 28;   // attn/wei LDS row stride; 112B rows, 16B-aligned
constexpr int MAIN_THREADS = 320;  // 5 waves
}

// ---------------------------------------------------------------------------
// Kernel 1: per-(i,b) fused attention + similarity. One block per pair.
//   sims[i*B+b] = log(sum_t e_t)   ; att_maps written for i==b blocks.
// ---------------------------------------------------------------------------
__global__ __launch_bounds__(MAIN_THREADS) void k_main(
    const float* __restrict__ ctx,    // (B,D,S)
    const float* __restrict__ words,  // (B,D,T)
    const int* __restrict__ cap_lens,
    float* __restrict__ sims,         // (B*B), [i][b]
    float* __restrict__ att_out)      // out+2: (B,T,S)
{
  __shared__ __align__(16) float Wl[Dn * WSTR];   // W[i]: [256][24], 24.0 KB
  __shared__ __align__(16) float AT[Sn * ASTR];   // attn e / wei: [289][28], 31.6 KB
  __shared__ float inv2[Tn];                      // 1/sum of softmax-2 per t
  __shared__ float red[Tn];                       // e_t terms

  const int bid = blockIdx.x;
  const int i = bid & 63;   // word batch index
  const int b = bid >> 6;   // image batch index (consecutive blocks share b -> L2 reuse)
  const int tid = threadIdx.x;
  const int len = cap_lens[i];  // uniform

  // ---- stage W[i] into LDS (layout identical to global: d-major, 24 floats/row)
  for (int idx = tid; idx < Dn * Tn; idx += MAIN_THREADS)
    Wl[idx] = words[(size_t)i * Dn * Tn + idx];
  __syncthreads();

  // ---- GEMM1: thread owns TWO s rows (halves LDS broadcasts per FMA).
  //      acc[2][24]; then per-row softmax over t in registers.
  if (tid < 145) {
    const int s0 = tid * 2;
    const int s1 = s0 + 1;
    const bool has2 = (s1 < Sn);   // tid==144 -> only s=288
    float a0[Tn], a1[Tn];
#pragma unroll
    for (int t = 0; t < Tn; ++t) { a0[t] = 0.f; a1[t] = 0.f; }
    const float* cb = ctx + (size_t)b * Dn * Sn;
    for (int d = 0; d < Dn; ++d) {
      const float* row = cb + (size_t)d * Sn;
      float v0 = row[s0];
      float v1 = has2 ? row[s1] : 0.f;
      const float* wr = &Wl[d * WSTR];
#pragma unroll
      for (int t = 0; t < Tn; ++t) {
        float w = wr[t];                 // wave-uniform LDS broadcast (b128 x6)
        a0[t] = fmaf(v0, w, a0[t]);
        a1[t] = fmaf(v1, w, a1[t]);
      }
    }
    // softmax over t (masked by cap_lens[i]); register-resident, per s-row
    {
      float m = NEGF;
#pragma unroll
      for (int t = 0; t < Tn; ++t)
        if (t < len) m = fmaxf(m, a0[t]);
      float sum = 0.f;
#pragma unroll
      for (int t = 0; t < Tn; ++t) {
        float e = (t < len) ? __expf(a0[t] - m) : 0.f;
        a0[t] = e; sum += e;
      }
      const float inv = 1.f / sum;
#pragma unroll
      for (int t = 0; t < Tn; ++t) AT[s0 * ASTR + t] = a0[t] * inv;
    }
    if (has2) {
      float m = NEGF;
#pragma unroll
      for (int t = 0; t < Tn; ++t)
        if (t < len) m = fmaxf(m, a1[t]);
      float sum = 0.f;
#pragma unroll
      for (int t = 0; t < Tn; ++t) {
        float e = (t < len) ? __expf(a1[t] - m) : 0.f;
        a1[t] = e; sum += e;
      }
      const float inv = 1.f / sum;
#pragma unroll
      for (int t = 0; t < Tn; ++t) AT[s1 * ASTR + t] = a1[t] * inv;
    }
  }
  __syncthreads();

  // ---- softmax over s (per t): 8 lanes per t, t<24 -> tids 0..191
  if (tid < Tn * 8) {
    const int t = tid >> 3, g = tid & 7;
    float m = NEGF;
    for (int ss = g; ss < Sn; ss += 8) m = fmaxf(m, AT[ss * ASTR + t]);
    m = fmaxf(m, __shfl_xor(m, 1));
    m = fmaxf(m, __shfl_xor(m, 2));
    m = fmaxf(m, __shfl_xor(m, 4));
    m *= G1;  // max(G1*p1) == G1*max(p1) exactly (G1 = 4.0, power of two)
    float sum = 0.f;
    for (int ss = g; ss < Sn; ss += 8) {
      float e = __expf(G1 * AT[ss * ASTR + t] - m);
      AT[ss * ASTR + t] = e;  // store unnormalized e in place
      sum += e;
    }
    sum += __shfl_xor(sum, 1);
    sum += __shfl_xor(sum, 2);
    sum += __shfl_xor(sum, 4);
    if (g == 0) inv2[t] = 1.f / sum;
  }
  __syncthreads();

  // ---- GEMM2: thread owns TWO d rows. wei[d][t] = inv2[t]*sum_s ctx[b][d][s]*e[s][t]
  //      ctx reads are per-lane contiguous streams (L2-resident, 64 blocks share b)
  float acc20[Tn], acc21[Tn];
  if (tid < 128) {
    const int d0 = tid * 2;
#pragma unroll
    for (int t = 0; t < Tn; ++t) { acc20[t] = 0.f; acc21[t] = 0.f; }
    const float* cg0 = ctx + ((size_t)b * Dn + d0) * Sn;
    const float* cg1 = cg0 + Sn;
    for (int ss = 0; ss < Sn; ++ss) {
      float v0 = cg0[ss];
      float v1 = cg1[ss];
      const float* er = &AT[ss * ASTR];
#pragma unroll
      for (int t = 0; t < Tn; ++t) {
        float e = er[t];                 // wave-uniform LDS broadcast (b128 x6)
        acc20[t] = fmaf(v0, e, acc20[t]);
        acc21[t] = fmaf(v1, e, acc21[t]);
      }
    }
#pragma unroll
    for (int t = 0; t < Tn; ++t) {
      acc20[t] *= inv2[t];
      acc21[t] *= inv2[t];
    }
  }

  // ---- att_maps for diagonal blocks (reads AT + inv2; before AT is reused)
  if (i == b) {
#pragma unroll 1
    for (int t = 0; t < Tn; ++t) {
      const float iv = inv2[t];
      for (int ss = tid; ss < Sn; ss += MAIN_THREADS)
        att_out[(size_t)i * Tn * Sn + (size_t)t * Sn + ss] = AT[ss * ASTR + t] * iv;
    }
  }
  __syncthreads();  // all AT (e) reads done

  // ---- store wei into AT space for the cross-d reductions
  if (tid < 128) {
    const int d0 = tid * 2;
#pragma unroll
    for (int t = 0; t < Tn; ++t) {
      AT[d0 * ASTR + t] = acc20[t];
      AT[(d0 + 1) * ASTR + t] = acc21[t];
    }
  }
  __syncthreads();

  // ---- per-t cosine similarity: num, |w|, |wei| reduced over d (8 lanes/t)
  if (tid < Tn * 8) {
    const int t = tid >> 3, g = tid & 7;
    float num = 0.f, wn = 0.f, vn = 0.f;
    for (int dd = g; dd < Dn; dd += 8) {
      float wv = Wl[dd * WSTR + t];
      float uv = AT[dd * ASTR + t];
      num = fmaf(wv, uv, num);
      wn = fmaf(wv, wv, wn);
      vn = fmaf(uv, uv, vn);
    }
    num += __shfl_xor(num, 1); num += __shfl_xor(num, 2); num += __shfl_xor(num, 4);
    wn  += __shfl_xor(wn, 1);  wn  += __shfl_xor(wn, 2);  wn  += __shfl_xor(wn, 4);
    vn  += __shfl_xor(vn, 1);  vn  += __shfl_xor(vn, 2);  vn  += __shfl_xor(vn, 4);
    if (g == 0) {
      float den = fmaxf(sqrtf(wn) * sqrtf(vn), EPSF);
      float rs = num / den;
      red[t] = (t < len) ? __expf(G2 * rs) : 0.f;
    }
  }
  __syncthreads();

  if (tid == 0) {
    float ssum = 0.f;
#pragma unroll
    for (int t = 0; t < Tn; ++t) ssum += red[t];
    sims[i * Bn + b] = logf(ssum);
  }
}

// ---------------------------------------------------------------------------
// Kernel 2: masked double log-softmax loss over the 64x64 sims matrix. 1 wave.
//   similarities[r][c] = sims[c*B + r] * G3  (masked NEG if same class, r!=c)
// ---------------------------------------------------------------------------
__global__ __launch_bounds__(64) void k_loss(const float* __restrict__ sims,
                                             const int* __restrict__ labels,
                                             const int* __restrict__ class_ids,
                                             float* __restrict__ out) {
  const int r = threadIdx.x;
  const int cr = class_ids[r];
  const int lab = labels[r];

  // ---- loss0: row r of `similarities`
  float m0 = NEGF;
  for (int c = 0; c < Bn; ++c) {
    float v = sims[c * Bn + r] * G3;
    if (class_ids[c] == cr && c != r) v = NEGF;
    m0 = fmaxf(m0, v);
  }
  float se0 = 0.f, tgt0 = 0.f;
  for (int c = 0; c < Bn; ++c) {
    float v = sims[c * Bn + r] * G3;
    if (class_ids[c] == cr && c != r) v = NEGF;
    se0 += __expf(v - m0);
    if (c == lab) tgt0 = v;
  }
  float val0 = tgt0 - (m0 + logf(se0));

  // ---- loss1: row r of similarities^T  (= column r)
  float m1 = NEGF;
  for (int c = 0; c < Bn; ++c) {
    float v = sims[r * Bn + c] * G3;
    if (class_ids[c] == cr && c != r) v = NEGF;
    m1 = fmaxf(m1, v);
  }
  float se1 = 0.f, tgt1 = 0.f;
  for (int c = 0; c < Bn; ++c) {
    float v = sims[r * Bn + c] * G3;
    if (class_ids[c] == cr && c != r) v = NEGF;
    se1 += __expf(v - m1);
    if (c == lab) tgt1 = v;
  }
  float val1 = tgt1 - (m1 + logf(se1));

  // wave-reduce the means
  for (int off = 1; off < 64; off <<= 1) {
    val0 += __shfl_xor(val0, off);
    val1 += __shfl_xor(val1, off);
  }
  if (r == 0) {
    out[0] = -val0 / (float)Bn;
    out[1] = -val1 / (float)Bn;
  }
}

// ---------------------------------------------------------------------------
extern "C" void kernel_launch(void* const* d_in, const int* in_sizes, int n_in,
                              void* d_out, int out_size, void* d_ws, size_t ws_size,
                              hipStream_t stream) {
  const float* img      = (const float*)d_in[0];  // (B,D,R,R)
  const float* words    = (const float*)d_in[1];  // (B,D,T)
  const int*   labels   = (const int*)d_in[2];
  const int*   cap_lens = (const int*)d_in[3];
  const int*   class_ids= (const int*)d_in[4];
  float* out = (float*)d_out;                     // [loss0, loss1, att_maps...]

  float* sims = (float*)d_ws;                     // B*B floats (16 KB)

  k_main<<<Bn * Bn, MAIN_THREADS, 0, stream>>>(img, words, cap_lens, sims, out + 2);

  k_loss<<<1, 64, 0, stream>>>(sims, labels, class_ids, out);
}

// Round 4
// 1111.381 us; speedup vs baseline: 1.7224x; 1.7224x over previous
//
#include <hip/hip_runtime.h>
#include <math.h>

// Problem constants (match reference)
namespace {
constexpr int Bn = 64;    // batch
constexpr int Dn = 256;   // feature dim
constexpr int Tn = 24;    // words
constexpr int Rn = 17;
constexpr int Sn = Rn * Rn;  // 289 spatial
constexpr float G1 = 4.0f, G2 = 5.0f, G3 = 10.0f;
constexpr float EPSF = 1e-8f;
constexpr float NEGF = -1e30f;
constexpr int WSTR = 24;   // W_lds row stride (96B rows, 16B-aligned)
constexpr int ASTR = 24;   // attn/wei LDS row stride (96B rows, 16B-aligned)
constexpr int NT = 320;    // 5 waves
}

__device__ __forceinline__ void fma24(float v, const float* __restrict__ row,
                                      float* __restrict__ acc) {
#pragma unroll
  for (int t = 0; t < Tn; ++t) acc[t] = fmaf(v, row[t], acc[t]);
}

// ---------------------------------------------------------------------------
// Kernel 0: transpose ctx (B,D,S) -> ctxT (B,S,D) so GEMM2 loads coalesce.
// ---------------------------------------------------------------------------
__global__ __launch_bounds__(256) void k_transpose(const float* __restrict__ ctx,
                                                   float* __restrict__ ctxT) {
  __shared__ float tile[32][33];  // +1 pad: conflict-free transpose
  const int b = blockIdx.z;
  const int x0 = blockIdx.x * 32;  // s
  const int y0 = blockIdx.y * 32;  // d (exact: 256/32)
  const int tx = threadIdx.x, ty = threadIdx.y;
  const float* src = ctx + (size_t)b * Dn * Sn;
  float* dst = ctxT + (size_t)b * Sn * Dn;
#pragma unroll
  for (int k = 0; k < 4; ++k) {
    int y = y0 + ty + k * 8, x = x0 + tx;
    if (x < Sn) tile[ty + k * 8][tx] = src[(size_t)y * Sn + x];
  }
  __syncthreads();
#pragma unroll
  for (int k = 0; k < 4; ++k) {
    int x = x0 + ty + k * 8, y = y0 + tx;  // x=s, y=d
    if (x < Sn) dst[(size_t)x * Dn + y] = tile[tx][ty + k * 8];
  }
}

// ---------------------------------------------------------------------------
// Kernel 1: per-(i,b) fused attention + similarity. One block per pair.
//   g2    : base pointer for GEMM2 operand (ctxT if ws fits, else ctx)
//   tstr  : element stride between d-rows of g2 (1 for ctxT, Sn for ctx)
//   sstr  : element stride between s-steps    (Dn for ctxT, 1  for ctx)
// ---------------------------------------------------------------------------
__global__ __launch_bounds__(NT) void k_main(
    const float* __restrict__ ctx,    // (B,D,S)
    const float* __restrict__ words,  // (B,D,T)
    const float* __restrict__ g2,
    int tstr, int sstr,
    const int* __restrict__ cap_lens,
    float* __restrict__ sims,         // (B*B), [i][b]
    float* __restrict__ att_out)      // out+2: (B,T,S)
{
  __shared__ __align__(16) float Wl[Dn * WSTR];   // 24.0 KB
  __shared__ __align__(16) float AT[Sn * ASTR];   // 27.1 KB
  __shared__ float inv2[Tn];
  __shared__ float red[Tn];

  const int bid = blockIdx.x;
  const int i = bid & 63;   // word batch index
  const int b = bid >> 6;   // image batch index (64 consecutive blocks share b)
  const int tid = threadIdx.x;
  const int len = cap_lens[i];  // uniform

  // ---- stage W[i] into LDS (float4 copy; both sides 16B-aligned)
  {
    const float4* wsrc = (const float4*)(words + (size_t)i * Dn * Tn);
    float4* wdst = (float4*)Wl;
    for (int k = tid; k < Dn * Tn / 4; k += NT) wdst[k] = wsrc[k];
  }
  __syncthreads();

  // ---- GEMM1: thread owns one s (289 active). 2-deep prefetch over d.
  if (tid < Sn) {
    float acc[Tn];
#pragma unroll
    for (int t = 0; t < Tn; ++t) acc[t] = 0.f;
    const float* cb = ctx + (size_t)b * Dn * Sn + tid;  // lane-coalesced
    float v0 = cb[0];
    float v1 = cb[Sn];
    int d = 0;
    for (; d < Dn - 2; d += 2) {
      float n0 = cb[(size_t)(d + 2) * Sn];
      float n1 = cb[(size_t)(d + 3) * Sn];
      fma24(v0, &Wl[d * WSTR], acc);
      fma24(v1, &Wl[(d + 1) * WSTR], acc);
      v0 = n0; v1 = n1;
    }
    fma24(v0, &Wl[d * WSTR], acc);
    fma24(v1, &Wl[(d + 1) * WSTR], acc);

    // softmax over t (masked); register-resident
    float m = NEGF;
#pragma unroll
    for (int t = 0; t < Tn; ++t)
      if (t < len) m = fmaxf(m, acc[t]);
    float sum = 0.f;
#pragma unroll
    for (int t = 0; t < Tn; ++t) {
      float e = (t < len) ? __expf(acc[t] - m) : 0.f;
      acc[t] = e; sum += e;
    }
    const float inv = 1.f / sum;
#pragma unroll
    for (int t = 0; t < Tn; ++t) AT[tid * ASTR + t] = acc[t] * inv;  // p1[s][t]
  }
  __syncthreads();

  // ---- softmax over s (per t): 8 lanes per t -> tids 0..191
  if (tid < Tn * 8) {
    const int t = tid >> 3, g = tid & 7;
    float m = NEGF;
    for (int ss = g; ss < Sn; ss += 8) m = fmaxf(m, AT[ss * ASTR + t]);
    m = fmaxf(m, __shfl_xor(m, 1));
    m = fmaxf(m, __shfl_xor(m, 2));
    m = fmaxf(m, __shfl_xor(m, 4));
    m *= G1;  // exact: G1 = 4.0 (power of two)
    float sum = 0.f;
    for (int ss = g; ss < Sn; ss += 8) {
      float e = __expf(G1 * AT[ss * ASTR + t] - m);
      AT[ss * ASTR + t] = e;  // unnormalized e in place
      sum += e;
    }
    sum += __shfl_xor(sum, 1);
    sum += __shfl_xor(sum, 2);
    sum += __shfl_xor(sum, 4);
    if (g == 0) inv2[t] = 1.f / sum;
  }
  __syncthreads();

  // ---- GEMM2: thread owns one d (256 active). 4-deep prefetch over s.
  float acc2[Tn];
  if (tid < Dn) {
#pragma unroll
    for (int t = 0; t < Tn; ++t) acc2[t] = 0.f;
    const float* src = g2 + (size_t)b * Dn * Sn + (size_t)tid * tstr;
    const size_t s1 = sstr, s2 = 2 * (size_t)sstr, s3 = 3 * (size_t)sstr,
                 s4 = 4 * (size_t)sstr;
    float p0 = src[0], p1 = src[s1], p2 = src[s2], p3 = src[s3];
    const float* nsrc = src + s4;
    int ss = 0;
    for (; ss < 284; ss += 4) {
      float n0 = nsrc[0], n1 = nsrc[s1], n2 = nsrc[s2], n3 = nsrc[s3];
      fma24(p0, &AT[ss * ASTR], acc2);
      fma24(p1, &AT[(ss + 1) * ASTR], acc2);
      fma24(p2, &AT[(ss + 2) * ASTR], acc2);
      fma24(p3, &AT[(ss + 3) * ASTR], acc2);
      p0 = n0; p1 = n1; p2 = n2; p3 = n3;
      nsrc += s4;
    }
    // ss = 284..287 (in p0..p3), then ss = 288
    fma24(p0, &AT[284 * ASTR], acc2);
    fma24(p1, &AT[285 * ASTR], acc2);
    fma24(p2, &AT[286 * ASTR], acc2);
    fma24(p3, &AT[287 * ASTR], acc2);
    {
      float v = src[(size_t)288 * sstr];
      fma24(v, &AT[288 * ASTR], acc2);
    }
#pragma unroll
    for (int t = 0; t < Tn; ++t) acc2[t] *= inv2[t];
  }

  // ---- att_maps for diagonal blocks (reads AT(e) + inv2, before AT reuse)
  if (i == b) {
#pragma unroll 1
    for (int t = 0; t < Tn; ++t) {
      const float iv = inv2[t];
      for (int ss = tid; ss < Sn; ss += NT)
        att_out[(size_t)i * Tn * Sn + (size_t)t * Sn + ss] = AT[ss * ASTR + t] * iv;
    }
  }
  __syncthreads();  // all e reads done

  // ---- store wei into AT space for cross-d reductions
  if (tid < Dn) {
#pragma unroll
    for (int t = 0; t < Tn; ++t) AT[tid * ASTR + t] = acc2[t];
  }
  __syncthreads();

  // ---- per-t cosine similarity over d (8 lanes per t)
  if (tid < Tn * 8) {
    const int t = tid >> 3, g = tid & 7;
    float num = 0.f, wn = 0.f, vn = 0.f;
    for (int dd = g; dd < Dn; dd += 8) {
      float wv = Wl[dd * WSTR + t];
      float uv = AT[dd * ASTR + t];
      num = fmaf(wv, uv, num);
      wn = fmaf(wv, wv, wn);
      vn = fmaf(uv, uv, vn);
    }
    num += __shfl_xor(num, 1); num += __shfl_xor(num, 2); num += __shfl_xor(num, 4);
    wn  += __shfl_xor(wn, 1);  wn  += __shfl_xor(wn, 2);  wn  += __shfl_xor(wn, 4);
    vn  += __shfl_xor(vn, 1);  vn  += __shfl_xor(vn, 2);  vn  += __shfl_xor(vn, 4);
    if (g == 0) {
      float den = fmaxf(sqrtf(wn) * sqrtf(vn), EPSF);
      float rs = num / den;
      red[t] = (t < len) ? __expf(G2 * rs) : 0.f;
    }
  }
  __syncthreads();

  if (tid == 0) {
    float ssum = 0.f;
#pragma unroll
    for (int t = 0; t < Tn; ++t) ssum += red[t];
    sims[i * Bn + b] = logf(ssum);
  }
}

// ---------------------------------------------------------------------------
// Kernel 2: masked double log-softmax loss over the 64x64 sims matrix. 1 wave.
// ---------------------------------------------------------------------------
__global__ __launch_bounds__(64) void k_loss(const float* __restrict__ sims,
                                             const int* __restrict__ labels,
                                             const int* __restrict__ class_ids,
                                             float* __restrict__ out) {
  const int r = threadIdx.x;
  const int cr = class_ids[r];
  const int lab = labels[r];

  float m0 = NEGF;
  for (int c = 0; c < Bn; ++c) {
    float v = sims[c * Bn + r] * G3;
    if (class_ids[c] == cr && c != r) v = NEGF;
    m0 = fmaxf(m0, v);
  }
  float se0 = 0.f, tgt0 = 0.f;
  for (int c = 0; c < Bn; ++c) {
    float v = sims[c * Bn + r] * G3;
    if (class_ids[c] == cr && c != r) v = NEGF;
    se0 += __expf(v - m0);
    if (c == lab) tgt0 = v;
  }
  float val0 = tgt0 - (m0 + logf(se0));

  float m1 = NEGF;
  for (int c = 0; c < Bn; ++c) {
    float v = sims[r * Bn + c] * G3;
    if (class_ids[c] == cr && c != r) v = NEGF;
    m1 = fmaxf(m1, v);
  }
  float se1 = 0.f, tgt1 = 0.f;
  for (int c = 0; c < Bn; ++c) {
    float v = sims[r * Bn + c] * G3;
    if (class_ids[c] == cr && c != r) v = NEGF;
    se1 += __expf(v - m1);
    if (c == lab) tgt1 = v;
  }
  float val1 = tgt1 - (m1 + logf(se1));

  for (int off = 1; off < 64; off <<= 1) {
    val0 += __shfl_xor(val0, off);
    val1 += __shfl_xor(val1, off);
  }
  if (r == 0) {
    out[0] = -val0 / (float)Bn;
    out[1] = -val1 / (float)Bn;
  }
}

// ---------------------------------------------------------------------------
extern "C" void kernel_launch(void* const* d_in, const int* in_sizes, int n_in,
                              void* d_out, int out_size, void* d_ws, size_t ws_size,
                              hipStream_t stream) {
  const float* img      = (const float*)d_in[0];  // (B,D,R,R)
  const float* words    = (const float*)d_in[1];  // (B,D,T)
  const int*   labels   = (const int*)d_in[2];
  const int*   cap_lens = (const int*)d_in[3];
  const int*   class_ids= (const int*)d_in[4];
  float* out = (float*)d_out;                     // [loss0, loss1, att_maps...]

  const size_t simsB = (size_t)Bn * Bn * sizeof(float);
  const size_t ctxTB = (size_t)Bn * Sn * Dn * sizeof(float);
  float* sims = (float*)d_ws;
  float* ctxT = (float*)((char*)d_ws + simsB);
  const bool useT = ws_size >= simsB + ctxTB;

  const float* g2 = img;
  int tstr = Sn, sstr = 1;  // fallback: direct (uncoalesced) GEMM2 reads
  if (useT) {
    dim3 tb(32, 8);
    dim3 tg((Sn + 31) / 32, Dn / 32, Bn);
    k_transpose<<<tg, tb, 0, stream>>>(img, ctxT);
    g2 = ctxT; tstr = 1; sstr = Dn;
  }

  k_main<<<Bn * Bn, NT, 0, stream>>>(img, words, g2, tstr, sstr,
                                     cap_lens, sims, out + 2);

  k_loss<<<1, 64, 0, stream>>>(sims, labels, class_ids, out);
}

// Round 6
// 546.688 us; speedup vs baseline: 3.5015x; 2.0329x over previous
//
#include <hip/hip_runtime.h>
#include <math.h>

// Problem constants (match reference)
namespace {
constexpr int Bn = 64;    // batch
constexpr int Dn = 256;   // feature dim
constexpr int Tn = 24;    // words
constexpr int Rn = 17;
constexpr int Sn = Rn * Rn;  // 289 spatial
constexpr float G1 = 4.0f, G2 = 5.0f, G3 = 10.0f;
constexpr float EPSF = 1e-8f;
constexpr float NEGF = -1e30f;
// MFMA-path geometry
constexpr int SP = 304;    // s padded to 19*16 (GEMM-A M)
constexpr int KP = 320;    // s padded to 10*32 (GEMM-B K)
constexpr int ESTR = 344;  // EH/EL row stride (shorts): 688 B, 16B-aligned rows
constexpr int PSTR = 305;  // P row stride (floats): 17 mod 32 -> spread banks
// VALU-fallback constants (round-4 kernel, known-correct)
constexpr int WSTR = 24;
constexpr int ASTR = 24;
constexpr int NT = 320;
}

typedef __attribute__((ext_vector_type(8))) short bf16x8;  // 8 bf16 (4 VGPRs)
typedef __attribute__((ext_vector_type(4))) float f32x4;   // 4 fp32 acc

#define MFMA_BF16 __builtin_amdgcn_mfma_f32_16x16x32_bf16

// RNE float -> bf16 bits (bit-twiddle; no NaN inputs here)
__device__ __forceinline__ short f2bf(float x) {
  unsigned u = __float_as_uint(x);
  return (short)((u + 0x7FFFu + ((u >> 16) & 1u)) >> 16);
}
__device__ __forceinline__ float bf2f(short h) {
  return __uint_as_float(((unsigned)(unsigned short)h) << 16);
}

// ---------------------------------------------------------------------------
// Prep 1: Ch/Cl = split-bf16 of ctx (B,D,S) padded to (B,D,KP). s-pad = 0.
// ---------------------------------------------------------------------------
__global__ __launch_bounds__(256) void kprep_C(const float* __restrict__ ctx,
                                               short* __restrict__ Ch,
                                               short* __restrict__ Cl) {
  const int total = Bn * Dn * KP;
  for (int idx = blockIdx.x * 256 + threadIdx.x; idx < total; idx += gridDim.x * 256) {
    int sp = idx % KP;
    int bd = idx / KP;  // b*Dn + d
    float v = (sp < Sn) ? ctx[(size_t)bd * Sn + sp] : 0.f;
    short h = f2bf(v);
    Ch[idx] = h;
    Cl[idx] = f2bf(v - bf2f(h));
  }
}

// ---------------------------------------------------------------------------
// Prep 2: Ah/Al = split-bf16 of ctx^T: (B,SP,D). Rows s>=289 are zero.
// ---------------------------------------------------------------------------
__global__ __launch_bounds__(256) void kprep_A(const float* __restrict__ ctx,
                                               short* __restrict__ Ah,
                                               short* __restrict__ Al) {
  __shared__ float tile[32][33];
  const int b = blockIdx.z;
  const int s0 = blockIdx.x * 32;
  const int d0 = blockIdx.y * 32;
  const int tx = threadIdx.x, ty = threadIdx.y;
  const float* src = ctx + (size_t)b * Dn * Sn;
#pragma unroll
  for (int k = 0; k < 4; ++k) {
    int d = d0 + ty + k * 8, s = s0 + tx;
    tile[ty + k * 8][tx] = (s < Sn) ? src[(size_t)d * Sn + s] : 0.f;
  }
  __syncthreads();
  short* dh = Ah + (size_t)b * SP * Dn;
  short* dl = Al + (size_t)b * SP * Dn;
#pragma unroll
  for (int k = 0; k < 4; ++k) {
    int s = s0 + ty + k * 8, d = d0 + tx;
    if (s < SP) {
      float v = tile[tx][ty + k * 8];
      short h = f2bf(v);
      dh[(size_t)s * Dn + d] = h;
      dl[(size_t)s * Dn + d] = f2bf(v - bf2f(h));
    }
  }
}

// ---------------------------------------------------------------------------
// Prep 3: Wh/Wl = split-bf16 of words^T per i: (B,32,D). Rows t>=24 zero.
// ---------------------------------------------------------------------------
__global__ __launch_bounds__(256) void kprep_W(const float* __restrict__ words,
                                               short* __restrict__ Wh,
                                               short* __restrict__ Wl) {
  const int i = blockIdx.x;
  for (int idx = threadIdx.x; idx < 32 * Dn; idx += 256) {
    int t = idx >> 8;   // /Dn
    int d = idx & 255;
    float v = (t < Tn) ? words[((size_t)i * Dn + d) * Tn + t] : 0.f;
    short h = f2bf(v);
    Wh[(size_t)i * 32 * Dn + idx] = h;
    Wl[(size_t)i * 32 * Dn + idx] = f2bf(v - bf2f(h));
  }
}

// ---------------------------------------------------------------------------
// Main MFMA kernel: one 512-thread block (8 waves) per (i,b) pair.
//   GEMM-A (304x32x256, split-bf16 x3) -> in-reg softmax over t ->
//   LDS transpose -> softmax over s -> e as split-bf16 in LDS ->
//   GEMM-B (256x32x320) -> cosine sim -> sims[i*B+b]. att_maps on i==b.
// Fragment layout (guide §3, m89-verified C/D):
//   A: row m = lane&15, k = (lane>>4)*8+e ; B: col n = lane&15, same k
//   C/D: col n = lane&15, row m = (lane>>4)*4 + reg
// ---------------------------------------------------------------------------
__global__ __launch_bounds__(512, 4) void k_main8(
    const short* __restrict__ Ah, const short* __restrict__ Al,
    const short* __restrict__ Ch, const short* __restrict__ Cl,
    const short* __restrict__ Wh, const short* __restrict__ Wl,
    const float* __restrict__ words, const int* __restrict__ cap_lens,
    float* __restrict__ sims, float* __restrict__ att_out)
{
  __shared__ __align__(16) float P[Tn][PSTR];    // 29,280 B  p1[t][s]
  __shared__ __align__(16) short EH[32][ESTR];   // 22,016 B  e2 hi
  __shared__ __align__(16) short EL[32][ESTR];   // 22,016 B  e2 lo
  __shared__ float inv2s[32];
  __shared__ float redN[Tn], redV[Tn], redW[Tn], redE[Tn];

  const int bid = blockIdx.x;
  const int i = bid & 63, b = bid >> 6;
  const int tid = threadIdx.x;
  const int lane = tid & 63;
  const int wv = tid >> 6;              // wave 0..7
  const int l15 = lane & 15, lg = lane >> 4;
  const int len = cap_lens[i];

  // ---- zero EH/EL (pad rows/cols MUST be 0 for GEMM-B) + reduction slots
  {
    int4* zh = (int4*)&EH[0][0];
    int4* zl = (int4*)&EL[0][0];
    const int n16 = 32 * ESTR * 2 / 16;  // 1376 int4 per buffer
    for (int k = tid; k < n16; k += 512) {
      zh[k] = make_int4(0, 0, 0, 0);
      zl[k] = make_int4(0, 0, 0, 0);
    }
    if (tid < Tn) { redN[tid] = 0.f; redV[tid] = 0.f; redW[tid] = 0.f; }
  }

  // ============ GEMM-A: logits[s][t] = sum_d ctxT[s][d] * W^T[t][d]
  f32x4 acc[3][2];
#pragma unroll
  for (int j = 0; j < 3; ++j) {
    acc[j][0] = f32x4{0.f, 0.f, 0.f, 0.f};
    acc[j][1] = f32x4{0.f, 0.f, 0.f, 0.f};
  }
  const size_t Abase = (size_t)b * SP * Dn;
  const size_t Wbase = (size_t)i * 32 * Dn;
#pragma unroll 2
  for (int kk = 0; kk < 8; ++kk) {
    const int k0 = kk * 32 + lg * 8;
    bf16x8 bh0 = *(const bf16x8*)&Wh[Wbase + (size_t)l15 * Dn + k0];
    bf16x8 bl0 = *(const bf16x8*)&Wl[Wbase + (size_t)l15 * Dn + k0];
    bf16x8 bh1 = *(const bf16x8*)&Wh[Wbase + (size_t)(16 + l15) * Dn + k0];
    bf16x8 bl1 = *(const bf16x8*)&Wl[Wbase + (size_t)(16 + l15) * Dn + k0];
#pragma unroll
    for (int j = 0; j < 3; ++j) {
      const int mt = wv + j * 8;            // wave's m-tiles: w, w+8, w+16
      if (mt < 19) {
        const size_t arow = Abase + (size_t)(mt * 16 + l15) * Dn + k0;
        bf16x8 ah = *(const bf16x8*)&Ah[arow];
        bf16x8 al = *(const bf16x8*)&Al[arow];
        acc[j][0] = MFMA_BF16(ah, bh0, acc[j][0], 0, 0, 0);
        acc[j][0] = MFMA_BF16(ah, bl0, acc[j][0], 0, 0, 0);
        acc[j][0] = MFMA_BF16(al, bh0, acc[j][0], 0, 0, 0);
        acc[j][1] = MFMA_BF16(ah, bh1, acc[j][1], 0, 0, 0);
        acc[j][1] = MFMA_BF16(ah, bl1, acc[j][1], 0, 0, 0);
        acc[j][1] = MFMA_BF16(al, bh1, acc[j][1], 0, 0, 0);
      }
    }
  }

  // ---- softmax-1 over t (masked t<len), fully in registers.
  //      Row s = mt*16 + lg*4 + q lives in the 16 lanes of group lg, reg q.
  const int t0 = l15, t1 = 16 + l15;
#pragma unroll
  for (int j = 0; j < 3; ++j) {
    const int mt = wv + j * 8;
    if (mt >= 19) continue;
    float mx[4], e0[4], e1[4], sum[4];
#pragma unroll
    for (int q = 0; q < 4; ++q) {
      float a = (t0 < len) ? acc[j][0][q] : NEGF;
      float c = (t1 < len) ? acc[j][1][q] : NEGF;
      mx[q] = fmaxf(a, c);
    }
#pragma unroll
    for (int q = 0; q < 4; ++q) {
      mx[q] = fmaxf(mx[q], __shfl_xor(mx[q], 1));
      mx[q] = fmaxf(mx[q], __shfl_xor(mx[q], 2));
      mx[q] = fmaxf(mx[q], __shfl_xor(mx[q], 4));
      mx[q] = fmaxf(mx[q], __shfl_xor(mx[q], 8));
    }
#pragma unroll
    for (int q = 0; q < 4; ++q) {
      e0[q] = (t0 < len) ? __expf(acc[j][0][q] - mx[q]) : 0.f;
      e1[q] = (t1 < len) ? __expf(acc[j][1][q] - mx[q]) : 0.f;
      sum[q] = e0[q] + e1[q];
    }
#pragma unroll
    for (int q = 0; q < 4; ++q) {
      sum[q] += __shfl_xor(sum[q], 1);
      sum[q] += __shfl_xor(sum[q], 2);
      sum[q] += __shfl_xor(sum[q], 4);
      sum[q] += __shfl_xor(sum[q], 8);
    }
#pragma unroll
    for (int q = 0; q < 4; ++q) {
      const int s = mt * 16 + lg * 4 + q;
      const float inv = 1.f / sum[q];
      P[t0][s] = (s < Sn) ? e0[q] * inv : 0.f;
      if (l15 < 8) P[t1][s] = (s < Sn) ? e1[q] * inv : 0.f;  // t 16..23
    }
  }
  __syncthreads();

  // ---- softmax-2 over s (per t); store unnormalized e2 as split-bf16.
  //      e2 in (0,1]; inv2 folded into GEMM-B epilogue.
  const int t2 = tid >> 4;      // 16 lanes per t
  const int g2i = tid & 15;
  if (t2 < Tn) {
    float mx = NEGF;
    for (int s = g2i; s < Sn; s += 16) mx = fmaxf(mx, P[t2][s]);
    mx = fmaxf(mx, __shfl_xor(mx, 1));
    mx = fmaxf(mx, __shfl_xor(mx, 2));
    mx = fmaxf(mx, __shfl_xor(mx, 4));
    mx = fmaxf(mx, __shfl_xor(mx, 8));
    mx *= G1;  // exact: G1 = 4.0 is a power of two
    float sum = 0.f;
    for (int s = g2i; s < Sn; s += 16) {
      float e = __expf(G1 * P[t2][s] - mx);
      short h = f2bf(e);
      EH[t2][s] = h;
      EL[t2][s] = f2bf(e - bf2f(h));
      sum += e;
    }
    sum += __shfl_xor(sum, 1);
    sum += __shfl_xor(sum, 2);
    sum += __shfl_xor(sum, 4);
    sum += __shfl_xor(sum, 8);
    const float sinv = 1.f / sum;
    if (g2i == 0) inv2s[t2] = sinv;
    if (i == b) {  // att_maps in full fp32 (recompute exp)
      float* ao = att_out + ((size_t)i * Tn + t2) * Sn;
      for (int s = g2i; s < Sn; s += 16)
        ao[s] = __expf(G1 * P[t2][s] - mx) * sinv;
    }
  }
  __syncthreads();

  // ============ GEMM-B: wei[d][t] = sum_s ctx[b][d][s] * e2[t][s]
  f32x4 acc2[2][2];
#pragma unroll
  for (int j = 0; j < 2; ++j) {
    acc2[j][0] = f32x4{0.f, 0.f, 0.f, 0.f};
    acc2[j][1] = f32x4{0.f, 0.f, 0.f, 0.f};
  }
  const size_t Cbase = (size_t)b * Dn * KP;
#pragma unroll 2
  for (int kk = 0; kk < 10; ++kk) {
    const int k0 = kk * 32 + lg * 8;
    bf16x8 bh0 = *(const bf16x8*)&EH[l15][k0];
    bf16x8 bl0 = *(const bf16x8*)&EL[l15][k0];
    bf16x8 bh1 = *(const bf16x8*)&EH[16 + l15][k0];
    bf16x8 bl1 = *(const bf16x8*)&EL[16 + l15][k0];
#pragma unroll
    for (int j = 0; j < 2; ++j) {
      const int d = (wv + j * 8) * 16 + l15;   // d-tiles: w, w+8
      const size_t crow = Cbase + (size_t)d * KP + k0;
      bf16x8 ah = *(const bf16x8*)&Ch[crow];
      bf16x8 al = *(const bf16x8*)&Cl[crow];
      acc2[j][0] = MFMA_BF16(ah, bh0, acc2[j][0], 0, 0, 0);
      acc2[j][0] = MFMA_BF16(ah, bl0, acc2[j][0], 0, 0, 0);
      acc2[j][0] = MFMA_BF16(al, bh0, acc2[j][0], 0, 0, 0);
      acc2[j][1] = MFMA_BF16(ah, bh1, acc2[j][1], 0, 0, 0);
      acc2[j][1] = MFMA_BF16(ah, bl1, acc2[j][1], 0, 0, 0);
      acc2[j][1] = MFMA_BF16(al, bh1, acc2[j][1], 0, 0, 0);
    }
  }

  // ---- cosine similarity: per t reduce num/|wei|^2/|w|^2 over d
  float pn[2] = {0.f, 0.f}, pv[2] = {0.f, 0.f}, pw[2] = {0.f, 0.f};
#pragma unroll
  for (int nt = 0; nt < 2; ++nt) {
    const int t = nt * 16 + l15;
    const bool tv = (t < Tn);
    const float iv = tv ? inv2s[t] : 0.f;
#pragma unroll
    for (int j = 0; j < 2; ++j) {
#pragma unroll
      for (int q = 0; q < 4; ++q) {
        const int d = (wv + j * 8) * 16 + lg * 4 + q;
        const float wei = acc2[j][nt][q] * iv;
        const float wvv = tv ? words[((size_t)i * Dn + d) * Tn + t] : 0.f;
        pn[nt] = fmaf(wvv, wei, pn[nt]);
        pv[nt] = fmaf(wei, wei, pv[nt]);
        pw[nt] = fmaf(wvv, wvv, pw[nt]);
      }
    }
  }
#pragma unroll
  for (int nt = 0; nt < 2; ++nt) {
    pn[nt] += __shfl_xor(pn[nt], 16); pn[nt] += __shfl_xor(pn[nt], 32);
    pv[nt] += __shfl_xor(pv[nt], 16); pv[nt] += __shfl_xor(pv[nt], 32);
    pw[nt] += __shfl_xor(pw[nt], 16); pw[nt] += __shfl_xor(pw[nt], 32);
  }
  if (lg == 0) {
#pragma unroll
    for (int nt = 0; nt < 2; ++nt) {
      const int t = nt * 16 + l15;
      if (t < Tn) {
        atomicAdd(&redN[t], pn[nt]);
        atomicAdd(&redV[t], pv[nt]);
        atomicAdd(&redW[t], pw[nt]);
      }
    }
  }
  __syncthreads();
  if (tid < Tn) {
    const float den = fmaxf(sqrtf(redW[tid]) * sqrtf(redV[tid]), EPSF);
    const float rs = redN[tid] / den;
    redE[tid] = (tid < len) ? __expf(G2 * rs) : 0.f;
  }
  __syncthreads();
  if (tid == 0) {
    float ssum = 0.f;
#pragma unroll
    for (int t = 0; t < Tn; ++t) ssum += redE[t];
    sims[i * Bn + b] = logf(ssum);
  }
}

// ---------------------------------------------------------------------------
// VALU fallback path (round-4 kernels, known-correct) — used if ws too small.
// ---------------------------------------------------------------------------
__device__ __forceinline__ void fma24(float v, const float* __restrict__ row,
                                      float* __restrict__ acc) {
#pragma unroll
  for (int t = 0; t < Tn; ++t) acc[t] = fmaf(v, row[t], acc[t]);
}

__global__ __launch_bounds__(256) void k_transpose(const float* __restrict__ ctx,
                                                   float* __restrict__ ctxT) {
  __shared__ float tile[32][33];
  const int b = blockIdx.z;
  const int x0 = blockIdx.x * 32;
  const int y0 = blockIdx.y * 32;
  const int tx = threadIdx.x, ty = threadIdx.y;
  const float* src = ctx + (size_t)b * Dn * Sn;
  float* dst = ctxT + (size_t)b * Sn * Dn;
#pragma unroll
  for (int k = 0; k < 4; ++k) {
    int y = y0 + ty + k * 8, x = x0 + tx;
    if (x < Sn) tile[ty + k * 8][tx] = src[(size_t)y * Sn + x];
  }
  __syncthreads();
#pragma unroll
  for (int k = 0; k < 4; ++k) {
    int x = x0 + ty + k * 8, y = y0 + tx;
    if (x < Sn) dst[(size_t)x * Dn + y] = tile[tx][ty + k * 8];
  }
}

__global__ __launch_bounds__(NT) void k_main_valu(
    const float* __restrict__ ctx, const float* __restrict__ words,
    const float* __restrict__ g2, int tstr, int sstr,
    const int* __restrict__ cap_lens,
    float* __restrict__ sims, float* __restrict__ att_out)
{
  __shared__ __align__(16) float Wl[Dn * WSTR];
  __shared__ __align__(16) float AT[Sn * ASTR];
  __shared__ float inv2[Tn];
  __shared__ float red[Tn];

  const int bid = blockIdx.x;
  const int i = bid & 63, b = bid >> 6;
  const int tid = threadIdx.x;
  const int len = cap_lens[i];

  {
    const float4* wsrc = (const float4*)(words + (size_t)i * Dn * Tn);
    float4* wdst = (float4*)Wl;
    for (int k = tid; k < Dn * Tn / 4; k += NT) wdst[k] = wsrc[k];
  }
  __syncthreads();

  if (tid < Sn) {
    float acc[Tn];
#pragma unroll
    for (int t = 0; t < Tn; ++t) acc[t] = 0.f;
    const float* cb = ctx + (size_t)b * Dn * Sn + tid;
    float v0 = cb[0], v1 = cb[Sn];
    int d = 0;
    for (; d < Dn - 2; d += 2) {
      float n0 = cb[(size_t)(d + 2) * Sn];
      float n1 = cb[(size_t)(d + 3) * Sn];
      fma24(v0, &Wl[d * WSTR], acc);
      fma24(v1, &Wl[(d + 1) * WSTR], acc);
      v0 = n0; v1 = n1;
    }
    fma24(v0, &Wl[d * WSTR], acc);
    fma24(v1, &Wl[(d + 1) * WSTR], acc);
    float m = NEGF;
#pragma unroll
    for (int t = 0; t < Tn; ++t)
      if (t < len) m = fmaxf(m, acc[t]);
    float sum = 0.f;
#pragma unroll
    for (int t = 0; t < Tn; ++t) {
      float e = (t < len) ? __expf(acc[t] - m) : 0.f;
      acc[t] = e; sum += e;
    }
    const float inv = 1.f / sum;
#pragma unroll
    for (int t = 0; t < Tn; ++t) AT[tid * ASTR + t] = acc[t] * inv;
  }
  __syncthreads();

  if (tid < Tn * 8) {
    const int t = tid >> 3, g = tid & 7;
    float m = NEGF;
    for (int ss = g; ss < Sn; ss += 8) m = fmaxf(m, AT[ss * ASTR + t]);
    m = fmaxf(m, __shfl_xor(m, 1));
    m = fmaxf(m, __shfl_xor(m, 2));
    m = fmaxf(m, __shfl_xor(m, 4));
    m *= G1;
    float sum = 0.f;
    for (int ss = g; ss < Sn; ss += 8) {
      float e = __expf(G1 * AT[ss * ASTR + t] - m);
      AT[ss * ASTR + t] = e;
      sum += e;
    }
    sum += __shfl_xor(sum, 1);
    sum += __shfl_xor(sum, 2);
    sum += __shfl_xor(sum, 4);
    if (g == 0) inv2[t] = 1.f / sum;
  }
  __syncthreads();

  float acc2[Tn];
  if (tid < Dn) {
#pragma unroll
    for (int t = 0; t < Tn; ++t) acc2[t] = 0.f;
    const float* src = g2 + (size_t)b * Dn * Sn + (size_t)tid * tstr;
    const size_t s1 = sstr, s2 = 2 * (size_t)sstr, s3 = 3 * (size_t)sstr,
                 s4 = 4 * (size_t)sstr;
    float p0 = src[0], p1 = src[s1], p2 = src[s2], p3 = src[s3];
    const float* nsrc = src + s4;
    int ss = 0;
    for (; ss < 284; ss += 4) {
      float n0 = nsrc[0], n1 = nsrc[s1], n2 = nsrc[s2], n3 = nsrc[s3];
      fma24(p0, &AT[ss * ASTR], acc2);
      fma24(p1, &AT[(ss + 1) * ASTR], acc2);
      fma24(p2, &AT[(ss + 2) * ASTR], acc2);
      fma24(p3, &AT[(ss + 3) * ASTR], acc2);
      p0 = n0; p1 = n1; p2 = n2; p3 = n3;
      nsrc += s4;
    }
    fma24(p0, &AT[284 * ASTR], acc2);
    fma24(p1, &AT[285 * ASTR], acc2);
    fma24(p2, &AT[286 * ASTR], acc2);
    fma24(p3, &AT[287 * ASTR], acc2);
    {
      float v = src[(size_t)288 * sstr];
      fma24(v, &AT[288 * ASTR], acc2);
    }
#pragma unroll
    for (int t = 0; t < Tn; ++t) acc2[t] *= inv2[t];
  }

  if (i == b) {
#pragma unroll 1
    for (int t = 0; t < Tn; ++t) {
      const float iv = inv2[t];
      for (int ss = tid; ss < Sn; ss += NT)
        att_out[(size_t)i * Tn * Sn + (size_t)t * Sn + ss] = AT[ss * ASTR + t] * iv;
    }
  }
  __syncthreads();

  if (tid < Dn) {
#pragma unroll
    for (int t = 0; t < Tn; ++t) AT[tid * ASTR + t] = acc2[t];
  }
  __syncthreads();

  if (tid < Tn * 8) {
    const int t = tid >> 3, g = tid & 7;
    float num = 0.f, wn = 0.f, vn = 0.f;
    for (int dd = g; dd < Dn; dd += 8) {
      float wvv = Wl[dd * WSTR + t];
      float uv = AT[dd * ASTR + t];
      num = fmaf(wvv, uv, num);
      wn = fmaf(wvv, wvv, wn);
      vn = fmaf(uv, uv, vn);
    }
    num += __shfl_xor(num, 1); num += __shfl_xor(num, 2); num += __shfl_xor(num, 4);
    wn  += __shfl_xor(wn, 1);  wn  += __shfl_xor(wn, 2);  wn  += __shfl_xor(wn, 4);
    vn  += __shfl_xor(vn, 1);  vn  += __shfl_xor(vn, 2);  vn  += __shfl_xor(vn, 4);
    if (g == 0) {
      float den = fmaxf(sqrtf(wn) * sqrtf(vn), EPSF);
      float rs = num / den;
      red[t] = (t < len) ? __expf(G2 * rs) : 0.f;
    }
  }
  __syncthreads();

  if (tid == 0) {
    float ssum = 0.f;
#pragma unroll
    for (int t = 0; t < Tn; ++t) ssum += red[t];
    sims[i * Bn + b] = logf(ssum);
  }
}

// ---------------------------------------------------------------------------
// Loss kernel: masked double log-softmax over 64x64 sims. 1 wave.
// ---------------------------------------------------------------------------
__global__ __launch_bounds__(64) void k_loss(const float* __restrict__ sims,
                                             const int* __restrict__ labels,
                                             const int* __restrict__ class_ids,
                                             float* __restrict__ out) {
  const int r = threadIdx.x;
  const int cr = class_ids[r];
  const int lab = labels[r];

  float m0 = NEGF;
  for (int c = 0; c < Bn; ++c) {
    float v = sims[c * Bn + r] * G3;
    if (class_ids[c] == cr && c != r) v = NEGF;
    m0 = fmaxf(m0, v);
  }
  float se0 = 0.f, tgt0 = 0.f;
  for (int c = 0; c < Bn; ++c) {
    float v = sims[c * Bn + r] * G3;
    if (class_ids[c] == cr && c != r) v = NEGF;
    se0 += __expf(v - m0);
    if (c == lab) tgt0 = v;
  }
  float val0 = tgt0 - (m0 + logf(se0));

  float m1 = NEGF;
  for (int c = 0; c < Bn; ++c) {
    float v = sims[r * Bn + c] * G3;
    if (class_ids[c] == cr && c != r) v = NEGF;
    m1 = fmaxf(m1, v);
  }
  float se1 = 0.f, tgt1 = 0.f;
  for (int c = 0; c < Bn; ++c) {
    float v = sims[r * Bn + c] * G3;
    if (class_ids[c] == cr && c != r) v = NEGF;
    se1 += __expf(v - m1);
    if (c == lab) tgt1 = v;
  }
  float val1 = tgt1 - (m1 + logf(se1));

  for (int off = 1; off < 64; off <<= 1) {
    val0 += __shfl_xor(val0, off);
    val1 += __shfl_xor(val1, off);
  }
  if (r == 0) {
    out[0] = -val0 / (float)Bn;
    out[1] = -val1 / (float)Bn;
  }
}

// ---------------------------------------------------------------------------
extern "C" void kernel_launch(void* const* d_in, const int* in_sizes, int n_in,
                              void* d_out, int out_size, void* d_ws, size_t ws_size,
                              hipStream_t stream) {
  const float* img      = (const float*)d_in[0];  // (B,D,R,R)
  const float* words    = (const float*)d_in[1];  // (B,D,T)
  const int*   labels   = (const int*)d_in[2];
  const int*   cap_lens = (const int*)d_in[3];
  const int*   class_ids= (const int*)d_in[4];
  float* out = (float*)d_out;                     // [loss0, loss1, att_maps...]

  float* sims = (float*)d_ws;
  size_t off = (size_t)Bn * Bn * sizeof(float);   // 16 KB
  const size_t AhB = (size_t)Bn * SP * Dn * 2;    // 9.96 MB each
  const size_t ChB = (size_t)Bn * Dn * KP * 2;    // 10.49 MB each
  const size_t WhB = (size_t)Bn * 32 * Dn * 2;    // 1.05 MB each
  short* Ah = (short*)((char*)d_ws + off); off += AhB;
  short* Al = (short*)((char*)d_ws + off); off += AhB;
  short* Ch = (short*)((char*)d_ws + off); off += ChB;
  short* Cl = (short*)((char*)d_ws + off); off += ChB;
  short* Wh = (short*)((char*)d_ws + off); off += WhB;
  short* Wl = (short*)((char*)d_ws + off); off += WhB;  // total ~43.0 MB

  if (ws_size >= off) {
    // MFMA path
    kprep_C<<<2048, 256, 0, stream>>>(img, Ch, Cl);
    kprep_A<<<dim3((SP + 31) / 32, Dn / 32, Bn), dim3(32, 8), 0, stream>>>(img, Ah, Al);
    kprep_W<<<Bn, 256, 0, stream>>>(words, Wh, Wl);
    k_main8<<<Bn * Bn, 512, 0, stream>>>(Ah, Al, Ch, Cl, Wh, Wl,
                                         words, cap_lens, sims, out + 2);
  } else {
    // VALU fallback (round-4 path)
    const size_t simsB = (size_t)Bn * Bn * sizeof(float);
    const size_t ctxTB = (size_t)Bn * Sn * Dn * sizeof(float);
    float* ctxT = (float*)((char*)d_ws + simsB);
    const bool useT = ws_size >= simsB + ctxTB;
    const float* g2 = img;
    int tstr = Sn, sstr = 1;
    if (useT) {
      dim3 tb(32, 8);
      dim3 tg((Sn + 31) / 32, Dn / 32, Bn);
      k_transpose<<<tg, tb, 0, stream>>>(img, ctxT);
      g2 = ctxT; tstr = 1; sstr = Dn;
    }
    k_main_valu<<<Bn * Bn, NT, 0, stream>>>(img, words, g2, tstr, sstr,
                                            cap_lens, sims, out + 2);
  }

  k_loss<<<1, 64, 0, stream>>>(sims, labels, class_ids, out);
}

// Round 7
// 271.216 us; speedup vs baseline: 7.0579x; 2.0157x over previous
//
#include <hip/hip_runtime.h>
#include <math.h>

// Problem constants (match reference)
namespace {
constexpr int Bn = 64;    // batch
constexpr int Dn = 256;   // feature dim
constexpr int Tn = 24;    // words
constexpr int Rn = 17;
constexpr int Sn = Rn * Rn;  // 289 spatial
constexpr float G1 = 4.0f, G2 = 5.0f, G3 = 10.0f;
constexpr float EPSF = 1e-8f;
constexpr float NEGF = -1e30f;
// MFMA-path geometry
constexpr int MT_A = 19;   // GEMM-A m-tiles (304 rows of s)
constexpr int KK_A = 8;    // GEMM-A k-steps (256 = 8*32 over d)
constexpr int DT_B = 16;   // GEMM-B m-tiles (256 rows of d)
constexpr int KK_B = 10;   // GEMM-B k-steps (320 = 10*32 over s)
constexpr int ESTR = 344;  // EH/EL row stride (shorts): 688 B rows
constexpr int PSTR = 305;  // P row stride (floats) inside union
// VALU-fallback constants (round-4 kernel, known-correct)
constexpr int WSTR = 24;
constexpr int ASTR = 24;
constexpr int NT = 320;
}

typedef __attribute__((ext_vector_type(8))) short bf16x8;  // 8 bf16 (4 VGPRs)
typedef __attribute__((ext_vector_type(4))) float f32x4;   // 4 fp32 acc

#define MFMA_BF16 __builtin_amdgcn_mfma_f32_16x16x32_bf16

// RNE float -> bf16 bits (bit-twiddle; no NaN inputs here)
__device__ __forceinline__ short f2bf(float x) {
  unsigned u = __float_as_uint(x);
  return (short)((u + 0x7FFFu + ((u >> 16) & 1u)) >> 16);
}
__device__ __forceinline__ float bf2f(short h) {
  return __uint_as_float(((unsigned)(unsigned short)h) << 16);
}

// ---------------------------------------------------------------------------
// Prep kernels: emit split-bf16 operands in FRAGMENT-ORDERED layout so every
// wave load in the main kernel is one contiguous 1KB transaction.
//   layout: [tile][kk][lane][8] shorts, offset = gid*8.
// ---------------------------------------------------------------------------
// A-frags (GEMM-A A-operand, ctx^T): lane(lg,l15) holds ctxT[mt*16+l15][kk*32+lg*8+e]
__global__ __launch_bounds__(256) void kprep_Af(const float* __restrict__ ctx,
                                                short* __restrict__ Ahf,
                                                short* __restrict__ Alf) {
  const int total = Bn * MT_A * KK_A * 64;
  for (int gid = blockIdx.x * 256 + threadIdx.x; gid < total; gid += gridDim.x * 256) {
    const int lane = gid & 63;
    int f = gid >> 6;
    const int kk = f & 7; f >>= 3;
    const int mt = f % MT_A;
    const int b = f / MT_A;
    const int s = mt * 16 + (lane & 15);
    const int d0 = kk * 32 + (lane >> 4) * 8;
    bf16x8 hi, lo;
#pragma unroll
    for (int e = 0; e < 8; ++e) {
      float v = (s < Sn) ? ctx[((size_t)b * Dn + d0 + e) * Sn + s] : 0.f;
      short h = f2bf(v);
      hi[e] = h;
      lo[e] = f2bf(v - bf2f(h));
    }
    *(bf16x8*)&Ahf[(size_t)gid * 8] = hi;
    *(bf16x8*)&Alf[(size_t)gid * 8] = lo;
  }
}

// C-frags (GEMM-B A-operand, ctx): lane holds ctx[dt*16+l15][kk*32+lg*8+e]
__global__ __launch_bounds__(256) void kprep_Cf(const float* __restrict__ ctx,
                                                short* __restrict__ Chf,
                                                short* __restrict__ Clf) {
  const int total = Bn * DT_B * KK_B * 64;
  for (int gid = blockIdx.x * 256 + threadIdx.x; gid < total; gid += gridDim.x * 256) {
    const int lane = gid & 63;
    int f = gid >> 6;
    const int kk = f % KK_B; f /= KK_B;
    const int dt = f & 15;
    const int b = f >> 4;
    const int d = dt * 16 + (lane & 15);
    const int s0 = kk * 32 + (lane >> 4) * 8;
    bf16x8 hi, lo;
#pragma unroll
    for (int e = 0; e < 8; ++e) {
      const int s = s0 + e;
      float v = (s < Sn) ? ctx[((size_t)b * Dn + d) * Sn + s] : 0.f;
      short h = f2bf(v);
      hi[e] = h;
      lo[e] = f2bf(v - bf2f(h));
    }
    *(bf16x8*)&Chf[(size_t)gid * 8] = hi;
    *(bf16x8*)&Clf[(size_t)gid * 8] = lo;
  }
}

// W-frags (GEMM-A B-operand, words^T): [i][kk][n][lane][8];
//   lane holds W[n*16+l15][kk*32+lg*8+e], W[t][d] = words[i][d][t]
__global__ __launch_bounds__(256) void kprep_Wf(const float* __restrict__ words,
                                                short* __restrict__ Whf,
                                                short* __restrict__ Wlf) {
  const int total = Bn * KK_A * 2 * 64;
  for (int gid = blockIdx.x * 256 + threadIdx.x; gid < total; gid += gridDim.x * 256) {
    const int lane = gid & 63;
    int f = gid >> 6;
    const int n = f & 1; f >>= 1;
    const int kk = f & 7;
    const int i = f >> 3;
    const int t = n * 16 + (lane & 15);
    const int d0 = kk * 32 + (lane >> 4) * 8;
    bf16x8 hi, lo;
#pragma unroll
    for (int e = 0; e < 8; ++e) {
      float v = (t < Tn) ? words[((size_t)i * Dn + d0 + e) * Tn + t] : 0.f;
      short h = f2bf(v);
      hi[e] = h;
      lo[e] = f2bf(v - bf2f(h));
    }
    *(bf16x8*)&Whf[(size_t)gid * 8] = hi;
    *(bf16x8*)&Wlf[(size_t)gid * 8] = lo;
  }
}

// ---------------------------------------------------------------------------
// Main MFMA kernel: one 512-thread block (8 waves) per (i,b) pair.
// LDS union: P (29.3KB, softmax-1 output) shares storage with EH/EL (44KB,
// split-bf16 e2) -- softmax-2 buffers its column in registers across a
// barrier. Total LDS ~44.5KB -> 3 blocks/CU (__launch_bounds__(512,6)).
// Fragment layout (guide §3, m89-verified C/D):
//   A: row m = lane&15, k = (lane>>4)*8+e ; B: col n = lane&15, same k
//   C/D: col n = lane&15, row m = (lane>>4)*4 + reg
// ---------------------------------------------------------------------------
__global__ __launch_bounds__(512, 6) void k_main8(
    const short* __restrict__ Ahf, const short* __restrict__ Alf,
    const short* __restrict__ Chf, const short* __restrict__ Clf,
    const short* __restrict__ Whf, const short* __restrict__ Wlf,
    const float* __restrict__ words, const int* __restrict__ cap_lens,
    float* __restrict__ sims, float* __restrict__ att_out)
{
  __shared__ __align__(16) short U[2][32][ESTR];  // 44,032 B: EH=U[0], EL=U[1]
  __shared__ float inv2s[32];
  __shared__ float redN[Tn], redV[Tn], redW[Tn], redE[Tn];
  float (*P)[PSTR] = (float (*)[PSTR]) & U[0][0][0];  // aliases U; dead before EH/EL live

  const int bid = blockIdx.x;
  const int i = bid & 63, b = bid >> 6;
  const int tid = threadIdx.x;
  const int lane = tid & 63;
  const int wv = tid >> 6;              // wave 0..7
  const int l15 = lane & 15, lg = lane >> 4;
  const int len = cap_lens[i];

  if (tid < Tn) { redN[tid] = 0.f; redV[tid] = 0.f; redW[tid] = 0.f; }

  // ============ GEMM-A: logits[s][t] = sum_d ctxT[s][d] * W^T[t][d]
  f32x4 acc[3][2];
#pragma unroll
  for (int j = 0; j < 3; ++j) {
    acc[j][0] = f32x4{0.f, 0.f, 0.f, 0.f};
    acc[j][1] = f32x4{0.f, 0.f, 0.f, 0.f};
  }
#pragma unroll 2
  for (int kk = 0; kk < KK_A; ++kk) {
    const size_t Wb = ((size_t)(i * KK_A + kk) * 2) * 512 + (size_t)lane * 8;
    bf16x8 bh0 = *(const bf16x8*)&Whf[Wb];
    bf16x8 bl0 = *(const bf16x8*)&Wlf[Wb];
    bf16x8 bh1 = *(const bf16x8*)&Whf[Wb + 512];
    bf16x8 bl1 = *(const bf16x8*)&Wlf[Wb + 512];
#pragma unroll
    for (int j = 0; j < 3; ++j) {
      const int mt = wv + j * 8;            // wave's m-tiles: w, w+8, w+16
      if (mt < MT_A) {
        const size_t Ab = ((size_t)(b * MT_A + mt) * KK_A + kk) * 512 + (size_t)lane * 8;
        bf16x8 ah = *(const bf16x8*)&Ahf[Ab];
        bf16x8 al = *(const bf16x8*)&Alf[Ab];
        __builtin_amdgcn_s_setprio(1);
        acc[j][0] = MFMA_BF16(ah, bh0, acc[j][0], 0, 0, 0);
        acc[j][0] = MFMA_BF16(ah, bl0, acc[j][0], 0, 0, 0);
        acc[j][0] = MFMA_BF16(al, bh0, acc[j][0], 0, 0, 0);
        acc[j][1] = MFMA_BF16(ah, bh1, acc[j][1], 0, 0, 0);
        acc[j][1] = MFMA_BF16(ah, bl1, acc[j][1], 0, 0, 0);
        acc[j][1] = MFMA_BF16(al, bh1, acc[j][1], 0, 0, 0);
        __builtin_amdgcn_s_setprio(0);
      }
    }
  }

  // ---- softmax-1 over t (masked t<len), fully in registers; write p1 to P.
  //      Row s = mt*16 + lg*4 + q lives in the 16 lanes of group lg, reg q.
  const int t0 = l15, t1 = 16 + l15;
#pragma unroll
  for (int j = 0; j < 3; ++j) {
    const int mt = wv + j * 8;
    if (mt >= MT_A) continue;
    float mx[4], e0[4], e1[4], sum[4];
#pragma unroll
    for (int q = 0; q < 4; ++q) {
      float a = (t0 < len) ? acc[j][0][q] : NEGF;
      float c = (t1 < len) ? acc[j][1][q] : NEGF;
      mx[q] = fmaxf(a, c);
    }
#pragma unroll
    for (int q = 0; q < 4; ++q) {
      mx[q] = fmaxf(mx[q], __shfl_xor(mx[q], 1));
      mx[q] = fmaxf(mx[q], __shfl_xor(mx[q], 2));
      mx[q] = fmaxf(mx[q], __shfl_xor(mx[q], 4));
      mx[q] = fmaxf(mx[q], __shfl_xor(mx[q], 8));
    }
#pragma unroll
    for (int q = 0; q < 4; ++q) {
      e0[q] = (t0 < len) ? __expf(acc[j][0][q] - mx[q]) : 0.f;
      e1[q] = (t1 < len) ? __expf(acc[j][1][q] - mx[q]) : 0.f;
      sum[q] = e0[q] + e1[q];
    }
#pragma unroll
    for (int q = 0; q < 4; ++q) {
      sum[q] += __shfl_xor(sum[q], 1);
      sum[q] += __shfl_xor(sum[q], 2);
      sum[q] += __shfl_xor(sum[q], 4);
      sum[q] += __shfl_xor(sum[q], 8);
    }
#pragma unroll
    for (int q = 0; q < 4; ++q) {
      const int s = mt * 16 + lg * 4 + q;
      const float inv = 1.f / sum[q];
      if (s < Sn) {
        P[t0][s] = e0[q] * inv;
        if (l15 < 8) P[t1][s] = e1[q] * inv;  // t 16..23
      }
    }
  }
  __syncthreads();  // P complete

  // ---- softmax-2 over s (per t), register-buffered so EH/EL can reuse P's LDS.
  //      Phase 1: read P column-set into regs, reduce max & sum. (reads only)
  const int t2 = tid >> 4;      // 16 lanes per t
  const int g2i = tid & 15;
  float ev[19];
  float sinv = 0.f;
  if (t2 < Tn) {
    float mx = NEGF;
#pragma unroll
    for (int k = 0; k < 19; ++k) {
      const int s = g2i + 16 * k;
      ev[k] = (s < Sn) ? P[t2][s] : NEGF;
      mx = fmaxf(mx, ev[k]);
    }
    mx = fmaxf(mx, __shfl_xor(mx, 1));
    mx = fmaxf(mx, __shfl_xor(mx, 2));
    mx = fmaxf(mx, __shfl_xor(mx, 4));
    mx = fmaxf(mx, __shfl_xor(mx, 8));
    mx *= G1;  // exact: G1 = 4.0 is a power of two
    float sum = 0.f;
#pragma unroll
    for (int k = 0; k < 19; ++k) {
      const int s = g2i + 16 * k;
      float e = (s < Sn) ? __expf(G1 * ev[k] - mx) : 0.f;
      ev[k] = e;  // overwrite with unnormalized e2
      sum += e;
    }
    sum += __shfl_xor(sum, 1);
    sum += __shfl_xor(sum, 2);
    sum += __shfl_xor(sum, 4);
    sum += __shfl_xor(sum, 8);
    sinv = 1.f / sum;
    if (g2i == 0) inv2s[t2] = sinv;
  }
  __syncthreads();  // all P reads done; U now owned by EH/EL

  // ---- Phase 2: write e2 split-bf16 into EH/EL; zero pad; att_maps on diag.
  if (t2 < Tn) {
#pragma unroll
    for (int k = 0; k < 19; ++k) {
      const int s = g2i + 16 * k;
      if (s < Sn) {
        float e = ev[k];
        short h = f2bf(e);
        U[0][t2][s] = h;
        U[1][t2][s] = f2bf(e - bf2f(h));
      }
    }
    if (i == b) {
      float* ao = att_out + ((size_t)i * Tn + t2) * Sn;
#pragma unroll
      for (int k = 0; k < 19; ++k) {
        const int s = g2i + 16 * k;
        if (s < Sn) ao[s] = ev[k] * sinv;
      }
    }
  }
  // zero k-pad cols [289,320) rows 0..23, and full rows 24..31 (both buffers)
  for (int idx = tid; idx < 24 * 31; idx += 512) {
    const int r = idx / 31, c = 289 + idx % 31;
    U[0][r][c] = 0; U[1][r][c] = 0;
  }
  for (int idx = tid; idx < 8 * ESTR; idx += 512) {
    const int r = 24 + idx / ESTR, c = idx % ESTR;
    U[0][r][c] = 0; U[1][r][c] = 0;
  }
  __syncthreads();

  // ============ GEMM-B: wei[d][t] = sum_s ctx[b][d][s] * e2[t][s]
  f32x4 acc2[2][2];
#pragma unroll
  for (int j = 0; j < 2; ++j) {
    acc2[j][0] = f32x4{0.f, 0.f, 0.f, 0.f};
    acc2[j][1] = f32x4{0.f, 0.f, 0.f, 0.f};
  }
#pragma unroll 2
  for (int kk = 0; kk < KK_B; ++kk) {
    const int k0 = kk * 32 + lg * 8;
    bf16x8 bh0 = *(const bf16x8*)&U[0][l15][k0];
    bf16x8 bl0 = *(const bf16x8*)&U[1][l15][k0];
    bf16x8 bh1 = *(const bf16x8*)&U[0][16 + l15][k0];
    bf16x8 bl1 = *(const bf16x8*)&U[1][16 + l15][k0];
#pragma unroll
    for (int j = 0; j < 2; ++j) {
      const int dt = wv + j * 8;            // d-tiles: w, w+8
      const size_t Cb = ((size_t)(b * DT_B + dt) * KK_B + kk) * 512 + (size_t)lane * 8;
      bf16x8 ah = *(const bf16x8*)&Chf[Cb];
      bf16x8 al = *(const bf16x8*)&Clf[Cb];
      __builtin_amdgcn_s_setprio(1);
      acc2[j][0] = MFMA_BF16(ah, bh0, acc2[j][0], 0, 0, 0);
      acc2[j][0] = MFMA_BF16(ah, bl0, acc2[j][0], 0, 0, 0);
      acc2[j][0] = MFMA_BF16(al, bh0, acc2[j][0], 0, 0, 0);
      acc2[j][1] = MFMA_BF16(ah, bh1, acc2[j][1], 0, 0, 0);
      acc2[j][1] = MFMA_BF16(ah, bl1, acc2[j][1], 0, 0, 0);
      acc2[j][1] = MFMA_BF16(al, bh1, acc2[j][1], 0, 0, 0);
      __builtin_amdgcn_s_setprio(0);
    }
  }

  // ---- cosine similarity: per t reduce num/|wei|^2/|w|^2 over d
  float pn[2] = {0.f, 0.f}, pv[2] = {0.f, 0.f}, pw[2] = {0.f, 0.f};
#pragma unroll
  for (int nt = 0; nt < 2; ++nt) {
    const int t = nt * 16 + l15;
    const bool tv = (t < Tn);
    const float iv = tv ? inv2s[t] : 0.f;
#pragma unroll
    for (int j = 0; j < 2; ++j) {
#pragma unroll
      for (int q = 0; q < 4; ++q) {
        const int d = (wv + j * 8) * 16 + lg * 4 + q;
        const float wei = acc2[j][nt][q] * iv;
        const float wvv = tv ? words[((size_t)i * Dn + d) * Tn + t] : 0.f;
        pn[nt] = fmaf(wvv, wei, pn[nt]);
        pv[nt] = fmaf(wei, wei, pv[nt]);
        pw[nt] = fmaf(wvv, wvv, pw[nt]);
      }
    }
  }
#pragma unroll
  for (int nt = 0; nt < 2; ++nt) {
    pn[nt] += __shfl_xor(pn[nt], 16); pn[nt] += __shfl_xor(pn[nt], 32);
    pv[nt] += __shfl_xor(pv[nt], 16); pv[nt] += __shfl_xor(pv[nt], 32);
    pw[nt] += __shfl_xor(pw[nt], 16); pw[nt] += __shfl_xor(pw[nt], 32);
  }
  if (lg == 0) {
#pragma unroll
    for (int nt = 0; nt < 2; ++nt) {
      const int t = nt * 16 + l15;
      if (t < Tn) {
        atomicAdd(&redN[t], pn[nt]);
        atomicAdd(&redV[t], pv[nt]);
        atomicAdd(&redW[t], pw[nt]);
      }
    }
  }
  __syncthreads();
  if (tid < Tn) {
    const float den = fmaxf(sqrtf(redW[tid]) * sqrtf(redV[tid]), EPSF);
    const float rs = redN[tid] / den;
    redE[tid] = (tid < len) ? __expf(G2 * rs) : 0.f;
  }
  __syncthreads();
  if (tid == 0) {
    float ssum = 0.f;
#pragma unroll
    for (int t = 0; t < Tn; ++t) ssum += redE[t];
    sims[i * Bn + b] = logf(ssum);
  }
}

// ---------------------------------------------------------------------------
// VALU fallback path (round-4 kernels, known-correct) — used if ws too small.
// ---------------------------------------------------------------------------
__device__ __forceinline__ void fma24(float v, const float* __restrict__ row,
                                      float* __restrict__ acc) {
#pragma unroll
  for (int t = 0; t < Tn; ++t) acc[t] = fmaf(v, row[t], acc[t]);
}

__global__ __launch_bounds__(256) void k_transpose(const float* __restrict__ ctx,
                                                   float* __restrict__ ctxT) {
  __shared__ float tile[32][33];
  const int b = blockIdx.z;
  const int x0 = blockIdx.x * 32;
  const int y0 = blockIdx.y * 32;
  const int tx = threadIdx.x, ty = threadIdx.y;
  const float* src = ctx + (size_t)b * Dn * Sn;
  float* dst = ctxT + (size_t)b * Sn * Dn;
#pragma unroll
  for (int k = 0; k < 4; ++k) {
    int y = y0 + ty + k * 8, x = x0 + tx;
    if (x < Sn) tile[ty + k * 8][tx] = src[(size_t)y * Sn + x];
  }
  __syncthreads();
#pragma unroll
  for (int k = 0; k < 4; ++k) {
    int x = x0 + ty + k * 8, y = y0 + tx;
    if (x < Sn) dst[(size_t)x * Dn + y] = tile[tx][ty + k * 8];
  }
}

__global__ __launch_bounds__(NT) void k_main_valu(
    const float* __restrict__ ctx, const float* __restrict__ words,
    const float* __restrict__ g2, int tstr, int sstr,
    const int* __restrict__ cap_lens,
    float* __restrict__ sims, float* __restrict__ att_out)
{
  __shared__ __align__(16) float Wl[Dn * WSTR];
  __shared__ __align__(16) float AT[Sn * ASTR];
  __shared__ float inv2[Tn];
  __shared__ float red[Tn];

  const int bid = blockIdx.x;
  const int i = bid & 63, b = bid >> 6;
  const int tid = threadIdx.x;
  const int len = cap_lens[i];

  {
    const float4* wsrc = (const float4*)(words + (size_t)i * Dn * Tn);
    float4* wdst = (float4*)Wl;
    for (int k = tid; k < Dn * Tn / 4; k += NT) wdst[k] = wsrc[k];
  }
  __syncthreads();

  if (tid < Sn) {
    float acc[Tn];
#pragma unroll
    for (int t = 0; t < Tn; ++t) acc[t] = 0.f;
    const float* cb = ctx + (size_t)b * Dn * Sn + tid;
    float v0 = cb[0], v1 = cb[Sn];
    int d = 0;
    for (; d < Dn - 2; d += 2) {
      float n0 = cb[(size_t)(d + 2) * Sn];
      float n1 = cb[(size_t)(d + 3) * Sn];
      fma24(v0, &Wl[d * WSTR], acc);
      fma24(v1, &Wl[(d + 1) * WSTR], acc);
      v0 = n0; v1 = n1;
    }
    fma24(v0, &Wl[d * WSTR], acc);
    fma24(v1, &Wl[(d + 1) * WSTR], acc);
    float m = NEGF;
#pragma unroll
    for (int t = 0; t < Tn; ++t)
      if (t < len) m = fmaxf(m, acc[t]);
    float sum = 0.f;
#pragma unroll
    for (int t = 0; t < Tn; ++t) {
      float e = (t < len) ? __expf(acc[t] - m) : 0.f;
      acc[t] = e; sum += e;
    }
    const float inv = 1.f / sum;
#pragma unroll
    for (int t = 0; t < Tn; ++t) AT[tid * ASTR + t] = acc[t] * inv;
  }
  __syncthreads();

  if (tid < Tn * 8) {
    const int t = tid >> 3, g = tid & 7;
    float m = NEGF;
    for (int ss = g; ss < Sn; ss += 8) m = fmaxf(m, AT[ss * ASTR + t]);
    m = fmaxf(m, __shfl_xor(m, 1));
    m = fmaxf(m, __shfl_xor(m, 2));
    m = fmaxf(m, __shfl_xor(m, 4));
    m *= G1;
    float sum = 0.f;
    for (int ss = g; ss < Sn; ss += 8) {
      float e = __expf(G1 * AT[ss * ASTR + t] - m);
      AT[ss * ASTR + t] = e;
      sum += e;
    }
    sum += __shfl_xor(sum, 1);
    sum += __shfl_xor(sum, 2);
    sum += __shfl_xor(sum, 4);
    if (g == 0) inv2[t] = 1.f / sum;
  }
  __syncthreads();

  float acc2[Tn];
  if (tid < Dn) {
#pragma unroll
    for (int t = 0; t < Tn; ++t) acc2[t] = 0.f;
    const float* src = g2 + (size_t)b * Dn * Sn + (size_t)tid * tstr;
    const size_t s1 = sstr, s2 = 2 * (size_t)sstr, s3 = 3 * (size_t)sstr,
                 s4 = 4 * (size_t)sstr;
    float p0 = src[0], p1 = src[s1], p2 = src[s2], p3 = src[s3];
    const float* nsrc = src + s4;
    int ss = 0;
    for (; ss < 284; ss += 4) {
      float n0 = nsrc[0], n1 = nsrc[s1], n2 = nsrc[s2], n3 = nsrc[s3];
      fma24(p0, &AT[ss * ASTR], acc2);
      fma24(p1, &AT[(ss + 1) * ASTR], acc2);
      fma24(p2, &AT[(ss + 2) * ASTR], acc2);
      fma24(p3, &AT[(ss + 3) * ASTR], acc2);
      p0 = n0; p1 = n1; p2 = n2; p3 = n3;
      nsrc += s4;
    }
    fma24(p0, &AT[284 * ASTR], acc2);
    fma24(p1, &AT[285 * ASTR], acc2);
    fma24(p2, &AT[286 * ASTR], acc2);
    fma24(p3, &AT[287 * ASTR], acc2);
    {
      float v = src[(size_t)288 * sstr];
      fma24(v, &AT[288 * ASTR], acc2);
    }
#pragma unroll
    for (int t = 0; t < Tn; ++t) acc2[t] *= inv2[t];
  }

  if (i == b) {
#pragma unroll 1
    for (int t = 0; t < Tn; ++t) {
      const float iv = inv2[t];
      for (int ss = tid; ss < Sn; ss += NT)
        att_out[(size_t)i * Tn * Sn + (size_t)t * Sn + ss] = AT[ss * ASTR + t] * iv;
    }
  }
  __syncthreads();

  if (tid < Dn) {
#pragma unroll
    for (int t = 0; t < Tn; ++t) AT[tid * ASTR + t] = acc2[t];
  }
  __syncthreads();

  if (tid < Tn * 8) {
    const int t = tid >> 3, g = tid & 7;
    float num = 0.f, wn = 0.f, vn = 0.f;
    for (int dd = g; dd < Dn; dd += 8) {
      float wvv = Wl[dd * WSTR + t];
      float uv = AT[dd * ASTR + t];
      num = fmaf(wvv, uv, num);
      wn = fmaf(wvv, wvv, wn);
      vn = fmaf(uv, uv, vn);
    }
    num += __shfl_xor(num, 1); num += __shfl_xor(num, 2); num += __shfl_xor(num, 4);
    wn  += __shfl_xor(wn, 1);  wn  += __shfl_xor(wn, 2);  wn  += __shfl_xor(wn, 4);
    vn  += __shfl_xor(vn, 1);  vn  += __shfl_xor(vn, 2);  vn  += __shfl_xor(vn, 4);
    if (g == 0) {
      float den = fmaxf(sqrtf(wn) * sqrtf(vn), EPSF);
      float rs = num / den;
      red[t] = (t < len) ? __expf(G2 * rs) : 0.f;
    }
  }
  __syncthreads();

  if (tid == 0) {
    float ssum = 0.f;
#pragma unroll
    for (int t = 0; t < Tn; ++t) ssum += red[t];
    sims[i * Bn + b] = logf(ssum);
  }
}

// ---------------------------------------------------------------------------
// Loss kernel: masked double log-softmax over 64x64 sims. 1 wave.
// ---------------------------------------------------------------------------
__global__ __launch_bounds__(64) void k_loss(const float* __restrict__ sims,
                                             const int* __restrict__ labels,
                                             const int* __restrict__ class_ids,
                                             float* __restrict__ out) {
  const int r = threadIdx.x;
  const int cr = class_ids[r];
  const int lab = labels[r];

  float m0 = NEGF;
  for (int c = 0; c < Bn; ++c) {
    float v = sims[c * Bn + r] * G3;
    if (class_ids[c] == cr && c != r) v = NEGF;
    m0 = fmaxf(m0, v);
  }
  float se0 = 0.f, tgt0 = 0.f;
  for (int c = 0; c < Bn; ++c) {
    float v = sims[c * Bn + r] * G3;
    if (class_ids[c] == cr && c != r) v = NEGF;
    se0 += __expf(v - m0);
    if (c == lab) tgt0 = v;
  }
  float val0 = tgt0 - (m0 + logf(se0));

  float m1 = NEGF;
  for (int c = 0; c < Bn; ++c) {
    float v = sims[r * Bn + c] * G3;
    if (class_ids[c] == cr && c != r) v = NEGF;
    m1 = fmaxf(m1, v);
  }
  float se1 = 0.f, tgt1 = 0.f;
  for (int c = 0; c < Bn; ++c) {
    float v = sims[r * Bn + c] * G3;
    if (class_ids[c] == cr && c != r) v = NEGF;
    se1 += __expf(v - m1);
    if (c == lab) tgt1 = v;
  }
  float val1 = tgt1 - (m1 + logf(se1));

  for (int off = 1; off < 64; off <<= 1) {
    val0 += __shfl_xor(val0, off);
    val1 += __shfl_xor(val1, off);
  }
  if (r == 0) {
    out[0] = -val0 / (float)Bn;
    out[1] = -val1 / (float)Bn;
  }
}

// ---------------------------------------------------------------------------
extern "C" void kernel_launch(void* const* d_in, const int* in_sizes, int n_in,
                              void* d_out, int out_size, void* d_ws, size_t ws_size,
                              hipStream_t stream) {
  const float* img      = (const float*)d_in[0];  // (B,D,R,R)
  const float* words    = (const float*)d_in[1];  // (B,D,T)
  const int*   labels   = (const int*)d_in[2];
  const int*   cap_lens = (const int*)d_in[3];
  const int*   class_ids= (const int*)d_in[4];
  float* out = (float*)d_out;                     // [loss0, loss1, att_maps...]

  float* sims = (float*)d_ws;
  size_t off = (size_t)Bn * Bn * sizeof(float);         // 16 KB
  const size_t AhB = (size_t)Bn * MT_A * KK_A * 512 * 2;  // 9.96 MB each
  const size_t ChB = (size_t)Bn * DT_B * KK_B * 512 * 2;  // 10.49 MB each
  const size_t WhB = (size_t)Bn * KK_A * 2 * 512 * 2;     // 1.05 MB each
  short* Ahf = (short*)((char*)d_ws + off); off += AhB;
  short* Alf = (short*)((char*)d_ws + off); off += AhB;
  short* Chf = (short*)((char*)d_ws + off); off += ChB;
  short* Clf = (short*)((char*)d_ws + off); off += ChB;
  short* Whf = (short*)((char*)d_ws + off); off += WhB;
  short* Wlf = (short*)((char*)d_ws + off); off += WhB;   // total ~43.0 MB

  if (ws_size >= off) {
    // MFMA path
    kprep_Af<<<(Bn * MT_A * KK_A * 64 + 255) / 256, 256, 0, stream>>>(img, Ahf, Alf);
    kprep_Cf<<<(Bn * DT_B * KK_B * 64 + 255) / 256, 256, 0, stream>>>(img, Chf, Clf);
    kprep_Wf<<<(Bn * KK_A * 2 * 64 + 255) / 256, 256, 0, stream>>>(words, Whf, Wlf);
    k_main8<<<Bn * Bn, 512, 0, stream>>>(Ahf, Alf, Chf, Clf, Whf, Wlf,
                                         words, cap_lens, sims, out + 2);
  } else {
    // VALU fallback (round-4 path)
    const size_t simsB = (size_t)Bn * Bn * sizeof(float);
    const size_t ctxTB = (size_t)Bn * Sn * Dn * sizeof(float);
    float* ctxT = (float*)((char*)d_ws + simsB);
    const bool useT = ws_size >= simsB + ctxTB;
    const float* g2 = img;
    int tstr = Sn, sstr = 1;
    if (useT) {
      dim3 tb(32, 8);
      dim3 tg((Sn + 31) / 32, Dn / 32, Bn);
      k_transpose<<<tg, tb, 0, stream>>>(img, ctxT);
      g2 = ctxT; tstr = 1; sstr = Dn;
    }
    k_main_valu<<<Bn * Bn, NT, 0, stream>>>(img, words, g2, tstr, sstr,
                                            cap_lens, sims, out + 2);
  }

  k_loss<<<1, 64, 0, stream>>>(sims, labels, class_ids, out);
}

// Round 8
// 268.180 us; speedup vs baseline: 7.1378x; 1.0113x over previous
//
#include <hip/hip_runtime.h>
#include <math.h>

// Problem constants (match reference)
namespace {
constexpr int Bn = 64;    // batch
constexpr int Dn = 256;   // feature dim
constexpr int Tn = 24;    // words
constexpr int Rn = 17;
constexpr int Sn = Rn * Rn;  // 289 spatial
constexpr float G1 = 4.0f, G2 = 5.0f, G3 = 10.0f;
constexpr float EPSF = 1e-8f;
constexpr float NEGF = -1e30f;
// MFMA-path geometry
constexpr int MT_A = 19;   // GEMM-A m-tiles (304 rows of s)
constexpr int KK_A = 8;    // GEMM-A k-steps (256 = 8*32 over d)
constexpr int DT_B = 16;   // GEMM-B m-tiles (256 rows of d)
constexpr int KK_B = 10;   // GEMM-B k-steps (320 = 10*32 over s)
constexpr int ESTR = 344;  // EH/EL row stride (shorts): 688 B rows
constexpr int PSTR = 305;  // P row stride (floats) inside union
constexpr int TSTR = 293;  // prep LDS tile stride (floats): odd mod 32 -> spread banks
// VALU-fallback constants (round-4 kernel, known-correct)
constexpr int WSTR = 24;
constexpr int ASTR = 24;
constexpr int NT = 320;
}

typedef __attribute__((ext_vector_type(8))) short bf16x8;  // 8 bf16 (4 VGPRs)
typedef __attribute__((ext_vector_type(4))) float f32x4;   // 4 fp32 acc

#define MFMA_BF16 __builtin_amdgcn_mfma_f32_16x16x32_bf16

// RNE float -> bf16 bits (bit-twiddle; no NaN inputs here)
__device__ __forceinline__ short f2bf(float x) {
  unsigned u = __float_as_uint(x);
  return (short)((u + 0x7FFFu + ((u >> 16) & 1u)) >> 16);
}
__device__ __forceinline__ float bf2f(short h) {
  return __uint_as_float(((unsigned)(unsigned short)h) << 16);
}

// ---------------------------------------------------------------------------
// Fused ctx prep: one block per (b, 32-wide d-block). Stages the fp32 tile
// ctx[b][d0:d0+32][0:289] in LDS once (coalesced), then emits BOTH
//   A-frags: [b][mt][kkA=d0/32][lane][8]   (ctx^T fragments, split-bf16)
//   C-frags: [b][dt=2/block][kk=0..9][lane][8] (ctx fragments, split-bf16)
// in fragment order so k_main8's loads are single 1KB wave transactions.
// ctx is read exactly once; all global writes are coalesced 16B/lane.
// ---------------------------------------------------------------------------
__global__ __launch_bounds__(256) void kprep_ctx(const float* __restrict__ ctx,
                                                 short* __restrict__ Ahf,
                                                 short* __restrict__ Alf,
                                                 short* __restrict__ Chf,
                                                 short* __restrict__ Clf) {
  __shared__ float tile[32][TSTR];  // 37.5 KB
  const int b = blockIdx.x >> 3;
  const int d0b = blockIdx.x & 7;   // d-block index (= GEMM-A k-step kkA)
  const int d0 = d0b * 32;
  const int tid = threadIdx.x;
  const int tx = tid & 31, ty = tid >> 5;

  // ---- stage: 32 lanes read 32 consecutive floats per row (coalesced)
  for (int r = ty; r < 32; r += 8) {
    const float* src = ctx + ((size_t)b * Dn + d0 + r) * Sn;
    for (int s = tx; s < Sn; s += 32) tile[r][s] = src[s];
  }
  __syncthreads();

  // ---- emit A-frags: 19 mt x 64 lanes; value e: tile[lg*8+e][mt*16+l15]
  //      (column reads; TSTR odd -> banks spread)
  for (int slot = tid; slot < MT_A * 64; slot += 256) {
    const int mt = slot >> 6;
    const int lane = slot & 63;
    const int s = mt * 16 + (lane & 15);
    const int dl = (lane >> 4) * 8;
    bf16x8 hi, lo;
#pragma unroll
    for (int e = 0; e < 8; ++e) {
      float v = (s < Sn) ? tile[dl + e][s] : 0.f;
      short h = f2bf(v);
      hi[e] = h;
      lo[e] = f2bf(v - bf2f(h));
    }
    const size_t gid = ((size_t)(b * MT_A + mt) * KK_A + d0b) * 64 + lane;
    *(bf16x8*)&Ahf[gid * 8] = hi;
    *(bf16x8*)&Alf[gid * 8] = lo;
  }

  // ---- emit C-frags: 2 dt x 10 kk x 64 lanes; value e: tile[dtl*16+l15][s0+e]
  //      (row reads, contiguous)
  for (int slot = tid; slot < 2 * KK_B * 64; slot += 256) {
    const int lane = slot & 63;
    const int f = slot >> 6;
    const int kk = f % KK_B;
    const int dtl = f / KK_B;
    const int dloc = dtl * 16 + (lane & 15);
    const int s0 = kk * 32 + (lane >> 4) * 8;
    bf16x8 hi, lo;
#pragma unroll
    for (int e = 0; e < 8; ++e) {
      const int s = s0 + e;
      float v = (s < Sn) ? tile[dloc][s] : 0.f;
      short h = f2bf(v);
      hi[e] = h;
      lo[e] = f2bf(v - bf2f(h));
    }
    const size_t gid = ((size_t)(b * DT_B + (d0b * 2 + dtl)) * KK_B + kk) * 64 + lane;
    *(bf16x8*)&Chf[gid * 8] = hi;
    *(bf16x8*)&Clf[gid * 8] = lo;
  }
}

// W-frags (GEMM-A B-operand, words^T): [i][kk][n][lane][8];
//   lane holds W[n*16+l15][kk*32+lg*8+e], W[t][d] = words[i][d][t]
__global__ __launch_bounds__(256) void kprep_Wf(const float* __restrict__ words,
                                                short* __restrict__ Whf,
                                                short* __restrict__ Wlf) {
  const int total = Bn * KK_A * 2 * 64;
  for (int gid = blockIdx.x * 256 + threadIdx.x; gid < total; gid += gridDim.x * 256) {
    const int lane = gid & 63;
    int f = gid >> 6;
    const int n = f & 1; f >>= 1;
    const int kk = f & 7;
    const int i = f >> 3;
    const int t = n * 16 + (lane & 15);
    const int d0 = kk * 32 + (lane >> 4) * 8;
    bf16x8 hi, lo;
#pragma unroll
    for (int e = 0; e < 8; ++e) {
      float v = (t < Tn) ? words[((size_t)i * Dn + d0 + e) * Tn + t] : 0.f;
      short h = f2bf(v);
      hi[e] = h;
      lo[e] = f2bf(v - bf2f(h));
    }
    *(bf16x8*)&Whf[(size_t)gid * 8] = hi;
    *(bf16x8*)&Wlf[(size_t)gid * 8] = lo;
  }
}

// ---------------------------------------------------------------------------
// Main MFMA kernel: one 512-thread block (8 waves) per (i,b) pair.
// (unchanged from round 7 — byte-identical so counters stay comparable)
// LDS union: P (29.3KB, softmax-1 output) shares storage with EH/EL (44KB,
// split-bf16 e2) -- softmax-2 buffers its column in registers across a
// barrier. Total LDS ~44.5KB -> 3 blocks/CU (__launch_bounds__(512,6)).
// Fragment layout (guide §3, m89-verified C/D):
//   A: row m = lane&15, k = (lane>>4)*8+e ; B: col n = lane&15, same k
//   C/D: col n = lane&15, row m = (lane>>4)*4 + reg
// ---------------------------------------------------------------------------
__global__ __launch_bounds__(512, 6) void k_main8(
    const short* __restrict__ Ahf, const short* __restrict__ Alf,
    const short* __restrict__ Chf, const short* __restrict__ Clf,
    const short* __restrict__ Whf, const short* __restrict__ Wlf,
    const float* __restrict__ words, const int* __restrict__ cap_lens,
    float* __restrict__ sims, float* __restrict__ att_out)
{
  __shared__ __align__(16) short U[2][32][ESTR];  // 44,032 B: EH=U[0], EL=U[1]
  __shared__ float inv2s[32];
  __shared__ float redN[Tn], redV[Tn], redW[Tn], redE[Tn];
  float (*P)[PSTR] = (float (*)[PSTR]) & U[0][0][0];  // aliases U; dead before EH/EL live

  const int bid = blockIdx.x;
  const int i = bid & 63, b = bid >> 6;
  const int tid = threadIdx.x;
  const int lane = tid & 63;
  const int wv = tid >> 6;              // wave 0..7
  const int l15 = lane & 15, lg = lane >> 4;
  const int len = cap_lens[i];

  if (tid < Tn) { redN[tid] = 0.f; redV[tid] = 0.f; redW[tid] = 0.f; }

  // ============ GEMM-A: logits[s][t] = sum_d ctxT[s][d] * W^T[t][d]
  f32x4 acc[3][2];
#pragma unroll
  for (int j = 0; j < 3; ++j) {
    acc[j][0] = f32x4{0.f, 0.f, 0.f, 0.f};
    acc[j][1] = f32x4{0.f, 0.f, 0.f, 0.f};
  }
#pragma unroll 2
  for (int kk = 0; kk < KK_A; ++kk) {
    const size_t Wb = ((size_t)(i * KK_A + kk) * 2) * 512 + (size_t)lane * 8;
    bf16x8 bh0 = *(const bf16x8*)&Whf[Wb];
    bf16x8 bl0 = *(const bf16x8*)&Wlf[Wb];
    bf16x8 bh1 = *(const bf16x8*)&Whf[Wb + 512];
    bf16x8 bl1 = *(const bf16x8*)&Wlf[Wb + 512];
#pragma unroll
    for (int j = 0; j < 3; ++j) {
      const int mt = wv + j * 8;            // wave's m-tiles: w, w+8, w+16
      if (mt < MT_A) {
        const size_t Ab = ((size_t)(b * MT_A + mt) * KK_A + kk) * 512 + (size_t)lane * 8;
        bf16x8 ah = *(const bf16x8*)&Ahf[Ab];
        bf16x8 al = *(const bf16x8*)&Alf[Ab];
        __builtin_amdgcn_s_setprio(1);
        acc[j][0] = MFMA_BF16(ah, bh0, acc[j][0], 0, 0, 0);
        acc[j][0] = MFMA_BF16(ah, bl0, acc[j][0], 0, 0, 0);
        acc[j][0] = MFMA_BF16(al, bh0, acc[j][0], 0, 0, 0);
        acc[j][1] = MFMA_BF16(ah, bh1, acc[j][1], 0, 0, 0);
        acc[j][1] = MFMA_BF16(ah, bl1, acc[j][1], 0, 0, 0);
        acc[j][1] = MFMA_BF16(al, bh1, acc[j][1], 0, 0, 0);
        __builtin_amdgcn_s_setprio(0);
      }
    }
  }

  // ---- softmax-1 over t (masked t<len), fully in registers; write p1 to P.
  //      Row s = mt*16 + lg*4 + q lives in the 16 lanes of group lg, reg q.
  const int t0 = l15, t1 = 16 + l15;
#pragma unroll
  for (int j = 0; j < 3; ++j) {
    const int mt = wv + j * 8;
    if (mt >= MT_A) continue;
    float mx[4], e0[4], e1[4], sum[4];
#pragma unroll
    for (int q = 0; q < 4; ++q) {
      float a = (t0 < len) ? acc[j][0][q] : NEGF;
      float c = (t1 < len) ? acc[j][1][q] : NEGF;
      mx[q] = fmaxf(a, c);
    }
#pragma unroll
    for (int q = 0; q < 4; ++q) {
      mx[q] = fmaxf(mx[q], __shfl_xor(mx[q], 1));
      mx[q] = fmaxf(mx[q], __shfl_xor(mx[q], 2));
      mx[q] = fmaxf(mx[q], __shfl_xor(mx[q], 4));
      mx[q] = fmaxf(mx[q], __shfl_xor(mx[q], 8));
    }
#pragma unroll
    for (int q = 0; q < 4; ++q) {
      e0[q] = (t0 < len) ? __expf(acc[j][0][q] - mx[q]) : 0.f;
      e1[q] = (t1 < len) ? __expf(acc[j][1][q] - mx[q]) : 0.f;
      sum[q] = e0[q] + e1[q];
    }
#pragma unroll
    for (int q = 0; q < 4; ++q) {
      sum[q] += __shfl_xor(sum[q], 1);
      sum[q] += __shfl_xor(sum[q], 2);
      sum[q] += __shfl_xor(sum[q], 4);
      sum[q] += __shfl_xor(sum[q], 8);
    }
#pragma unroll
    for (int q = 0; q < 4; ++q) {
      const int s = mt * 16 + lg * 4 + q;
      const float inv = 1.f / sum[q];
      if (s < Sn) {
        P[t0][s] = e0[q] * inv;
        if (l15 < 8) P[t1][s] = e1[q] * inv;  // t 16..23
      }
    }
  }
  __syncthreads();  // P complete

  // ---- softmax-2 over s (per t), register-buffered so EH/EL can reuse P's LDS.
  //      Phase 1: read P column-set into regs, reduce max & sum. (reads only)
  const int t2 = tid >> 4;      // 16 lanes per t
  const int g2i = tid & 15;
  float ev[19];
  float sinv = 0.f;
  if (t2 < Tn) {
    float mx = NEGF;
#pragma unroll
    for (int k = 0; k < 19; ++k) {
      const int s = g2i + 16 * k;
      ev[k] = (s < Sn) ? P[t2][s] : NEGF;
      mx = fmaxf(mx, ev[k]);
    }
    mx = fmaxf(mx, __shfl_xor(mx, 1));
    mx = fmaxf(mx, __shfl_xor(mx, 2));
    mx = fmaxf(mx, __shfl_xor(mx, 4));
    mx = fmaxf(mx, __shfl_xor(mx, 8));
    mx *= G1;  // exact: G1 = 4.0 is a power of two
    float sum = 0.f;
#pragma unroll
    for (int k = 0; k < 19; ++k) {
      const int s = g2i + 16 * k;
      float e = (s < Sn) ? __expf(G1 * ev[k] - mx) : 0.f;
      ev[k] = e;  // overwrite with unnormalized e2
      sum += e;
    }
    sum += __shfl_xor(sum, 1);
    sum += __shfl_xor(sum, 2);
    sum += __shfl_xor(sum, 4);
    sum += __shfl_xor(sum, 8);
    sinv = 1.f / sum;
    if (g2i == 0) inv2s[t2] = sinv;
  }
  __syncthreads();  // all P reads done; U now owned by EH/EL

  // ---- Phase 2: write e2 split-bf16 into EH/EL; zero pad; att_maps on diag.
  if (t2 < Tn) {
#pragma unroll
    for (int k = 0; k < 19; ++k) {
      const int s = g2i + 16 * k;
      if (s < Sn) {
        float e = ev[k];
        short h = f2bf(e);
        U[0][t2][s] = h;
        U[1][t2][s] = f2bf(e - bf2f(h));
      }
    }
    if (i == b) {
      float* ao = att_out + ((size_t)i * Tn + t2) * Sn;
#pragma unroll
      for (int k = 0; k < 19; ++k) {
        const int s = g2i + 16 * k;
        if (s < Sn) ao[s] = ev[k] * sinv;
      }
    }
  }
  // zero k-pad cols [289,320) rows 0..23, and full rows 24..31 (both buffers)
  for (int idx = tid; idx < 24 * 31; idx += 512) {
    const int r = idx / 31, c = 289 + idx % 31;
    U[0][r][c] = 0; U[1][r][c] = 0;
  }
  for (int idx = tid; idx < 8 * ESTR; idx += 512) {
    const int r = 24 + idx / ESTR, c = idx % ESTR;
    U[0][r][c] = 0; U[1][r][c] = 0;
  }
  __syncthreads();

  // ============ GEMM-B: wei[d][t] = sum_s ctx[b][d][s] * e2[t][s]
  f32x4 acc2[2][2];
#pragma unroll
  for (int j = 0; j < 2; ++j) {
    acc2[j][0] = f32x4{0.f, 0.f, 0.f, 0.f};
    acc2[j][1] = f32x4{0.f, 0.f, 0.f, 0.f};
  }
#pragma unroll 2
  for (int kk = 0; kk < KK_B; ++kk) {
    const int k0 = kk * 32 + lg * 8;
    bf16x8 bh0 = *(const bf16x8*)&U[0][l15][k0];
    bf16x8 bl0 = *(const bf16x8*)&U[1][l15][k0];
    bf16x8 bh1 = *(const bf16x8*)&U[0][16 + l15][k0];
    bf16x8 bl1 = *(const bf16x8*)&U[1][16 + l15][k0];
#pragma unroll
    for (int j = 0; j < 2; ++j) {
      const int dt = wv + j * 8;            // d-tiles: w, w+8
      const size_t Cb = ((size_t)(b * DT_B + dt) * KK_B + kk) * 512 + (size_t)lane * 8;
      bf16x8 ah = *(const bf16x8*)&Chf[Cb];
      bf16x8 al = *(const bf16x8*)&Clf[Cb];
      __builtin_amdgcn_s_setprio(1);
      acc2[j][0] = MFMA_BF16(ah, bh0, acc2[j][0], 0, 0, 0);
      acc2[j][0] = MFMA_BF16(ah, bl0, acc2[j][0], 0, 0, 0);
      acc2[j][0] = MFMA_BF16(al, bh0, acc2[j][0], 0, 0, 0);
      acc2[j][1] = MFMA_BF16(ah, bh1, acc2[j][1], 0, 0, 0);
      acc2[j][1] = MFMA_BF16(ah, bl1, acc2[j][1], 0, 0, 0);
      acc2[j][1] = MFMA_BF16(al, bh1, acc2[j][1], 0, 0, 0);
      __builtin_amdgcn_s_setprio(0);
    }
  }

  // ---- cosine similarity: per t reduce num/|wei|^2/|w|^2 over d
  float pn[2] = {0.f, 0.f}, pv[2] = {0.f, 0.f}, pw[2] = {0.f, 0.f};
#pragma unroll
  for (int nt = 0; nt < 2; ++nt) {
    const int t = nt * 16 + l15;
    const bool tv = (t < Tn);
    const float iv = tv ? inv2s[t] : 0.f;
#pragma unroll
    for (int j = 0; j < 2; ++j) {
#pragma unroll
      for (int q = 0; q < 4; ++q) {
        const int d = (wv + j * 8) * 16 + lg * 4 + q;
        const float wei = acc2[j][nt][q] * iv;
        const float wvv = tv ? words[((size_t)i * Dn + d) * Tn + t] : 0.f;
        pn[nt] = fmaf(wvv, wei, pn[nt]);
        pv[nt] = fmaf(wei, wei, pv[nt]);
        pw[nt] = fmaf(wvv, wvv, pw[nt]);
      }
    }
  }
#pragma unroll
  for (int nt = 0; nt < 2; ++nt) {
    pn[nt] += __shfl_xor(pn[nt], 16); pn[nt] += __shfl_xor(pn[nt], 32);
    pv[nt] += __shfl_xor(pv[nt], 16); pv[nt] += __shfl_xor(pv[nt], 32);
    pw[nt] += __shfl_xor(pw[nt], 16); pw[nt] += __shfl_xor(pw[nt], 32);
  }
  if (lg == 0) {
#pragma unroll
    for (int nt = 0; nt < 2; ++nt) {
      const int t = nt * 16 + l15;
      if (t < Tn) {
        atomicAdd(&redN[t], pn[nt]);
        atomicAdd(&redV[t], pv[nt]);
        atomicAdd(&redW[t], pw[nt]);
      }
    }
  }
  __syncthreads();
  if (tid < Tn) {
    const float den = fmaxf(sqrtf(redW[tid]) * sqrtf(redV[tid]), EPSF);
    const float rs = redN[tid] / den;
    redE[tid] = (tid < len) ? __expf(G2 * rs) : 0.f;
  }
  __syncthreads();
  if (tid == 0) {
    float ssum = 0.f;
#pragma unroll
    for (int t = 0; t < Tn; ++t) ssum += redE[t];
    sims[i * Bn + b] = logf(ssum);
  }
}

// ---------------------------------------------------------------------------
// VALU fallback path (round-4 kernels, known-correct) — used if ws too small.
// ---------------------------------------------------------------------------
__device__ __forceinline__ void fma24(float v, const float* __restrict__ row,
                                      float* __restrict__ acc) {
#pragma unroll
  for (int t = 0; t < Tn; ++t) acc[t] = fmaf(v, row[t], acc[t]);
}

__global__ __launch_bounds__(256) void k_transpose(const float* __restrict__ ctx,
                                                   float* __restrict__ ctxT) {
  __shared__ float tile[32][33];
  const int b = blockIdx.z;
  const int x0 = blockIdx.x * 32;
  const int y0 = blockIdx.y * 32;
  const int tx = threadIdx.x, ty = threadIdx.y;
  const float* src = ctx + (size_t)b * Dn * Sn;
  float* dst = ctxT + (size_t)b * Sn * Dn;
#pragma unroll
  for (int k = 0; k < 4; ++k) {
    int y = y0 + ty + k * 8, x = x0 + tx;
    if (x < Sn) tile[ty + k * 8][tx] = src[(size_t)y * Sn + x];
  }
  __syncthreads();
#pragma unroll
  for (int k = 0; k < 4; ++k) {
    int x = x0 + ty + k * 8, y = y0 + tx;
    if (x < Sn) dst[(size_t)x * Dn + y] = tile[tx][ty + k * 8];
  }
}

__global__ __launch_bounds__(NT) void k_main_valu(
    const float* __restrict__ ctx, const float* __restrict__ words,
    const float* __restrict__ g2, int tstr, int sstr,
    const int* __restrict__ cap_lens,
    float* __restrict__ sims, float* __restrict__ att_out)
{
  __shared__ __align__(16) float Wl[Dn * WSTR];
  __shared__ __align__(16) float AT[Sn * ASTR];
  __shared__ float inv2[Tn];
  __shared__ float red[Tn];

  const int bid = blockIdx.x;
  const int i = bid & 63, b = bid >> 6;
  const int tid = threadIdx.x;
  const int len = cap_lens[i];

  {
    const float4* wsrc = (const float4*)(words + (size_t)i * Dn * Tn);
    float4* wdst = (float4*)Wl;
    for (int k = tid; k < Dn * Tn / 4; k += NT) wdst[k] = wsrc[k];
  }
  __syncthreads();

  if (tid < Sn) {
    float acc[Tn];
#pragma unroll
    for (int t = 0; t < Tn; ++t) acc[t] = 0.f;
    const float* cb = ctx + (size_t)b * Dn * Sn + tid;
    float v0 = cb[0], v1 = cb[Sn];
    int d = 0;
    for (; d < Dn - 2; d += 2) {
      float n0 = cb[(size_t)(d + 2) * Sn];
      float n1 = cb[(size_t)(d + 3) * Sn];
      fma24(v0, &Wl[d * WSTR], acc);
      fma24(v1, &Wl[(d + 1) * WSTR], acc);
      v0 = n0; v1 = n1;
    }
    fma24(v0, &Wl[d * WSTR], acc);
    fma24(v1, &Wl[(d + 1) * WSTR], acc);
    float m = NEGF;
#pragma unroll
    for (int t = 0; t < Tn; ++t)
      if (t < len) m = fmaxf(m, acc[t]);
    float sum = 0.f;
#pragma unroll
    for (int t = 0; t < Tn; ++t) {
      float e = (t < len) ? __expf(acc[t] - m) : 0.f;
      acc[t] = e; sum += e;
    }
    const float inv = 1.f / sum;
#pragma unroll
    for (int t = 0; t < Tn; ++t) AT[tid * ASTR + t] = acc[t] * inv;
  }
  __syncthreads();

  if (tid < Tn * 8) {
    const int t = tid >> 3, g = tid & 7;
    float m = NEGF;
    for (int ss = g; ss < Sn; ss += 8) m = fmaxf(m, AT[ss * ASTR + t]);
    m = fmaxf(m, __shfl_xor(m, 1));
    m = fmaxf(m, __shfl_xor(m, 2));
    m = fmaxf(m, __shfl_xor(m, 4));
    m *= G1;
    float sum = 0.f;
    for (int ss = g; ss < Sn; ss += 8) {
      float e = __expf(G1 * AT[ss * ASTR + t] - m);
      AT[ss * ASTR + t] = e;
      sum += e;
    }
    sum += __shfl_xor(sum, 1);
    sum += __shfl_xor(sum, 2);
    sum += __shfl_xor(sum, 4);
    if (g == 0) inv2[t] = 1.f / sum;
  }
  __syncthreads();

  float acc2[Tn];
  if (tid < Dn) {
#pragma unroll
    for (int t = 0; t < Tn; ++t) acc2[t] = 0.f;
    const float* src = g2 + (size_t)b * Dn * Sn + (size_t)tid * tstr;
    const size_t s1 = sstr, s2 = 2 * (size_t)sstr, s3 = 3 * (size_t)sstr,
                 s4 = 4 * (size_t)sstr;
    float p0 = src[0], p1 = src[s1], p2 = src[s2], p3 = src[s3];
    const float* nsrc = src + s4;
    int ss = 0;
    for (; ss < 284; ss += 4) {
      float n0 = nsrc[0], n1 = nsrc[s1], n2 = nsrc[s2], n3 = nsrc[s3];
      fma24(p0, &AT[ss * ASTR], acc2);
      fma24(p1, &AT[(ss + 1) * ASTR], acc2);
      fma24(p2, &AT[(ss + 2) * ASTR], acc2);
      fma24(p3, &AT[(ss + 3) * ASTR], acc2);
      p0 = n0; p1 = n1; p2 = n2; p3 = n3;
      nsrc += s4;
    }
    fma24(p0, &AT[284 * ASTR], acc2);
    fma24(p1, &AT[285 * ASTR], acc2);
    fma24(p2, &AT[286 * ASTR], acc2);
    fma24(p3, &AT[287 * ASTR], acc2);
    {
      float v = src[(size_t)288 * sstr];
      fma24(v, &AT[288 * ASTR], acc2);
    }
#pragma unroll
    for (int t = 0; t < Tn; ++t) acc2[t] *= inv2[t];
  }

  if (i == b) {
#pragma unroll 1
    for (int t = 0; t < Tn; ++t) {
      const float iv = inv2[t];
      for (int ss = tid; ss < Sn; ss += NT)
        att_out[(size_t)i * Tn * Sn + (size_t)t * Sn + ss] = AT[ss * ASTR + t] * iv;
    }
  }
  __syncthreads();

  if (tid < Dn) {
#pragma unroll
    for (int t = 0; t < Tn; ++t) AT[tid * ASTR + t] = acc2[t];
  }
  __syncthreads();

  if (tid < Tn * 8) {
    const int t = tid >> 3, g = tid & 7;
    float num = 0.f, wn = 0.f, vn = 0.f;
    for (int dd = g; dd < Dn; dd += 8) {
      float wvv = Wl[dd * WSTR + t];
      float uv = AT[dd * ASTR + t];
      num = fmaf(wvv, uv, num);
      wn = fmaf(wvv, wvv, wn);
      vn = fmaf(uv, uv, vn);
    }
    num += __shfl_xor(num, 1); num += __shfl_xor(num, 2); num += __shfl_xor(num, 4);
    wn  += __shfl_xor(wn, 1);  wn  += __shfl_xor(wn, 2);  wn  += __shfl_xor(wn, 4);
    vn  += __shfl_xor(vn, 1);  vn  += __shfl_xor(vn, 2);  vn  += __shfl_xor(vn, 4);
    if (g == 0) {
      float den = fmaxf(sqrtf(wn) * sqrtf(vn), EPSF);
      float rs = num / den;
      red[t] = (t < len) ? __expf(G2 * rs) : 0.f;
    }
  }
  __syncthreads();

  if (tid == 0) {
    float ssum = 0.f;
#pragma unroll
    for (int t = 0; t < Tn; ++t) ssum += red[t];
    sims[i * Bn + b] = logf(ssum);
  }
}

// ---------------------------------------------------------------------------
// Loss kernel: masked double log-softmax over 64x64 sims. 1 wave.
// ---------------------------------------------------------------------------
__global__ __launch_bounds__(64) void k_loss(const float* __restrict__ sims,
                                             const int* __restrict__ labels,
                                             const int* __restrict__ class_ids,
                                             float* __restrict__ out) {
  const int r = threadIdx.x;
  const int cr = class_ids[r];
  const int lab = labels[r];

  float m0 = NEGF;
  for (int c = 0; c < Bn; ++c) {
    float v = sims[c * Bn + r] * G3;
    if (class_ids[c] == cr && c != r) v = NEGF;
    m0 = fmaxf(m0, v);
  }
  float se0 = 0.f, tgt0 = 0.f;
  for (int c = 0; c < Bn; ++c) {
    float v = sims[c * Bn + r] * G3;
    if (class_ids[c] == cr && c != r) v = NEGF;
    se0 += __expf(v - m0);
    if (c == lab) tgt0 = v;
  }
  float val0 = tgt0 - (m0 + logf(se0));

  float m1 = NEGF;
  for (int c = 0; c < Bn; ++c) {
    float v = sims[r * Bn + c] * G3;
    if (class_ids[c] == cr && c != r) v = NEGF;
    m1 = fmaxf(m1, v);
  }
  float se1 = 0.f, tgt1 = 0.f;
  for (int c = 0; c < Bn; ++c) {
    float v = sims[r * Bn + c] * G3;
    if (class_ids[c] == cr && c != r) v = NEGF;
    se1 += __expf(v - m1);
    if (c == lab) tgt1 = v;
  }
  float val1 = tgt1 - (m1 + logf(se1));

  for (int off = 1; off < 64; off <<= 1) {
    val0 += __shfl_xor(val0, off);
    val1 += __shfl_xor(val1, off);
  }
  if (r == 0) {
    out[0] = -val0 / (float)Bn;
    out[1] = -val1 / (float)Bn;
  }
}

// ---------------------------------------------------------------------------
extern "C" void kernel_launch(void* const* d_in, const int* in_sizes, int n_in,
                              void* d_out, int out_size, void* d_ws, size_t ws_size,
                              hipStream_t stream) {
  const float* img      = (const float*)d_in[0];  // (B,D,R,R)
  const float* words    = (const float*)d_in[1];  // (B,D,T)
  const int*   labels   = (const int*)d_in[2];
  const int*   cap_lens = (const int*)d_in[3];
  const int*   class_ids= (const int*)d_in[4];
  float* out = (float*)d_out;                     // [loss0, loss1, att_maps...]

  float* sims = (float*)d_ws;
  size_t off = (size_t)Bn * Bn * sizeof(float);         // 16 KB
  const size_t AhB = (size_t)Bn * MT_A * KK_A * 512 * 2;  // 9.96 MB each
  const size_t ChB = (size_t)Bn * DT_B * KK_B * 512 * 2;  // 10.49 MB each
  const size_t WhB = (size_t)Bn * KK_A * 2 * 512 * 2;     // 1.05 MB each
  short* Ahf = (short*)((char*)d_ws + off); off += AhB;
  short* Alf = (short*)((char*)d_ws + off); off += AhB;
  short* Chf = (short*)((char*)d_ws + off); off += ChB;
  short* Clf = (short*)((char*)d_ws + off); off += ChB;
  short* Whf = (short*)((char*)d_ws + off); off += WhB;
  short* Wlf = (short*)((char*)d_ws + off); off += WhB;   // total ~43.0 MB

  if (ws_size >= off) {
    // MFMA path: one fused ctx prep (ctx read once, all writes coalesced)
    kprep_ctx<<<Bn * 8, 256, 0, stream>>>(img, Ahf, Alf, Chf, Clf);
    kprep_Wf<<<(Bn * KK_A * 2 * 64 + 255) / 256, 256, 0, stream>>>(words, Whf, Wlf);
    k_main8<<<Bn * Bn, 512, 0, stream>>>(Ahf, Alf, Chf, Clf, Whf, Wlf,
                                         words, cap_lens, sims, out + 2);
  } else {
    // VALU fallback (round-4 path)
    const size_t simsB = (size_t)Bn * Bn * sizeof(float);
    const size_t ctxTB = (size_t)Bn * Sn * Dn * sizeof(float);
    float* ctxT = (float*)((char*)d_ws + simsB);
    const bool useT = ws_size >= simsB + ctxTB;
    const float* g2 = img;
    int tstr = Sn, sstr = 1;
    if (useT) {
      dim3 tb(32, 8);
      dim3 tg((Sn + 31) / 32, Dn / 32, Bn);
      k_transpose<<<tg, tb, 0, stream>>>(img, ctxT);
      g2 = ctxT; tstr = 1; sstr = Dn;
    }
    k_main_valu<<<Bn * Bn, NT, 0, stream>>>(img, words, g2, tstr, sstr,
                                            cap_lens, sims, out + 2);
  }

  k_loss<<<1, 64, 0, stream>>>(sims, labels, class_ids, out);
}